// Round 9
// baseline (440.525 us; speedup 1.0000x reference)
//
#include <hip/hip_runtime.h>

typedef __bf16 bf16_t;
typedef __bf16 bf16x4 __attribute__((ext_vector_type(4)));
typedef __bf16 bf16x8 __attribute__((ext_vector_type(8)));
typedef float  f32x4  __attribute__((ext_vector_type(4)));

// Problem constants (setup_inputs: b=2, t=8, C=768, h=w=16)
static constexpr int NHEADS = 12, HC = 64, HW = 256, SEQ = 2048;
static constexpr size_t QKV_ONE = (size_t)2 * NHEADS * SEQ * HC;   // 3145728 elems per q/k/v slab
static constexpr size_t NSTRIDE = 768 * 256;                        // 196608

// ---------------------------------------------------------------------------
// zero the attention accumulators (d_ws is poisoned 0xAA before every launch)
// ---------------------------------------------------------------------------
__global__ __launch_bounds__(256) void va_zero(float4* __restrict__ p, int n4) {
    int i = blockIdx.x * 256 + threadIdx.x;
    if (i < n4) p[i] = make_float4(0.f, 0.f, 0.f, 0.f);
}

// ---------------------------------------------------------------------------
// mp_weight for BOTH weights in one launch.
// ---------------------------------------------------------------------------
__global__ __launch_bounds__(256) void va_norm_w(const float* __restrict__ wqkv,
                                                 const float* __restrict__ wproj,
                                                 bf16_t* __restrict__ out) {
    int row = blockIdx.x;
    const float* wr = (row < 2304) ? wqkv + (size_t)row * 768
                                   : wproj + (size_t)(row - 2304) * 768;
    float part = 0.f;
    for (int i = threadIdx.x; i < 768; i += 256) { float v = wr[i]; part += v * v; }
#pragma unroll
    for (int off = 32; off > 0; off >>= 1) part += __shfl_down(part, off, 64);
    __shared__ float red[4];
    if ((threadIdx.x & 63) == 0) red[threadIdx.x >> 6] = part;
    __syncthreads();
    if (threadIdx.x == 0) {
        float s = red[0] + red[1] + red[2] + red[3];
        red[0] = 1.0f / (2.7712813e-3f + sqrtf(s));   // EPS*sqrt(768) + ||w||
    }
    __syncthreads();
    float sc = red[0];
    for (int i = threadIdx.x; i < 768; i += 256)
        out[(size_t)row * 768 + i] = (bf16_t)(wr[i] * sc);
}

// ---------------------------------------------------------------------------
// x fp32 [n][768 c][256 p]  ->  xt bf16 [n][256 p][768 c]
// ---------------------------------------------------------------------------
__global__ __launch_bounds__(256) void va_x2bf(const float* __restrict__ x,
                                               bf16_t* __restrict__ xt) {
    int n  = blockIdx.z;
    int c0 = blockIdx.x * 32;
    int p0 = blockIdx.y * 32;
    __shared__ float sm[32][33];
    int tx = threadIdx.x & 31, ty = threadIdx.x >> 5;
    const float* xp = x + (size_t)n * NSTRIDE;
#pragma unroll
    for (int i = 0; i < 4; i++)
        sm[ty + i * 8][tx] = xp[(size_t)(c0 + ty + i * 8) * 256 + p0 + tx];
    __syncthreads();
    bf16_t* xo = xt + (size_t)n * NSTRIDE;
#pragma unroll
    for (int i = 0; i < 4; i++)
        xo[(size_t)(p0 + ty + i * 8) * 768 + c0 + tx] = (bf16_t)sm[tx][ty + i * 8];
}

// ---------------------------------------------------------------------------
// QKV GEMM via MFMA, RoPE + q-scale fused in epilogue. (unchanged)
// ---------------------------------------------------------------------------
__global__ __launch_bounds__(256, 4) void va_qkv_mfma(const bf16_t* __restrict__ Wb,
                                                      const bf16_t* __restrict__ xt,
                                                      bf16_t* __restrict__ qkvb) {
    int n  = blockIdx.z;
    int m0 = blockIdx.y * 128;
    int p0 = blockIdx.x * 128;
    int tid = threadIdx.x;
    int lane = tid & 63, w = tid >> 6;
    int lo = lane & 15, hi = lane >> 4;
    int wm = w >> 1, wn = w & 1;

    const bf16_t* Ap = Wb + (size_t)(m0 + wm * 64 + lo) * 768 + hi * 8;
    const bf16_t* Bp = xt + (size_t)n * NSTRIDE + (size_t)(p0 + wn * 64 + lo) * 768 + hi * 8;

    f32x4 acc[4][4];
#pragma unroll
    for (int mt = 0; mt < 4; mt++)
#pragma unroll
        for (int nt = 0; nt < 4; nt++) acc[mt][nt] = (f32x4){0.f, 0.f, 0.f, 0.f};

    for (int k0 = 0; k0 < 768; k0 += 32) {
        bf16x8 af[4], bf[4];
#pragma unroll
        for (int mt = 0; mt < 4; mt++)
            af[mt] = *(const bf16x8*)(Ap + (size_t)mt * 16 * 768 + k0);
#pragma unroll
        for (int nt = 0; nt < 4; nt++)
            bf[nt] = *(const bf16x8*)(Bp + (size_t)nt * 16 * 768 + k0);
#pragma unroll
        for (int mt = 0; mt < 4; mt++)
#pragma unroll
            for (int nt = 0; nt < 4; nt++)
                acc[mt][nt] = __builtin_amdgcn_mfma_f32_16x16x32_bf16(af[mt], bf[nt], acc[mt][nt], 0, 0, 0);
    }

    int head_global = (m0 + wm * 64) >> 6;
    int qkv_idx = head_global / 12;
    int head    = head_global % 12;
    int b = n >> 3, tt = n & 7;
    int bm = b * 12 + head;
    if (qkv_idx < 2) {
        float qsc = (qkv_idx == 0) ? 0.125f : 1.0f;
        float ttf = (float)tt;
#pragma unroll
        for (int mt = 0; mt < 2; mt++)
#pragma unroll
            for (int r = 0; r < 4; r++) {
                int j = mt * 16 + hi * 4 + r;
                float ang = ttf * __expf(-(float)j * 0.2878231366242557f);
                float cs = __cosf(ang), sn = __sinf(ang);
#pragma unroll
                for (int nt = 0; nt < 4; nt++) {
                    float x1 = acc[mt][nt][r], x2 = acc[mt + 2][nt][r];
                    acc[mt][nt][r]     = (x1 * cs - x2 * sn) * qsc;
                    acc[mt + 2][nt][r] = (x1 * sn + x2 * cs) * qsc;
                }
            }
        bf16_t* dst = qkvb + (size_t)qkv_idx * QKV_ONE + ((size_t)bm * SEQ + (size_t)tt * HW) * HC;
#pragma unroll
        for (int mt = 0; mt < 4; mt++)
#pragma unroll
            for (int nt = 0; nt < 4; nt++)
#pragma unroll
                for (int r = 0; r < 4; r++) {
                    int cc = mt * 16 + hi * 4 + r;
                    int p  = p0 + wn * 64 + nt * 16 + lo;
                    dst[(size_t)p * HC + cc] = (bf16_t)acc[mt][nt][r];
                }
    } else {
        bf16_t* dst = qkvb + 2 * QKV_ONE + (size_t)bm * HC * SEQ + (size_t)tt * HW;
#pragma unroll
        for (int mt = 0; mt < 4; mt++)
#pragma unroll
            for (int nt = 0; nt < 4; nt++)
#pragma unroll
                for (int r = 0; r < 4; r++) {
                    int cc = mt * 16 + hi * 4 + r;
                    int p  = p0 + wn * 64 + nt * 16 + lo;
                    dst[(size_t)cc * SEQ + p] = (bf16_t)acc[mt][nt][r];
                }
    }
}

// ---------------------------------------------------------------------------
// MFMA flash attention v4: block-level split-K (no-max softmax => partials
// are plain sums). Grid = (36 (f,kf) pairs, 24 bm); every block identical:
// 4 key tiles x 256 queries, 4 waves sharing LDS-staged K/V (loaded once).
// Partial O (fp32) and l accumulated into global via atomicAdd; merged by
// va_merge. 864 uniform blocks => ~3 co-resident blocks/CU hide the
// per-tile latency chain that serialized v3.
// ---------------------------------------------------------------------------
__global__ __launch_bounds__(256, 3) void va_attn(const bf16_t* __restrict__ qkvb,
                                                  float* __restrict__ Oacc,
                                                  float* __restrict__ lacc) {
    int pidx = blockIdx.x;         // 0..35  -> (f, kf<=f)
    int bm   = blockIdx.y;         // 0..23
    int f = 0;
    while ((f + 1) * (f + 2) / 2 <= pidx) f++;
    int kf = pidx - f * (f + 1) / 2;

    int tid = threadIdx.x;
    int w = tid >> 6, lane = tid & 63;
    int lo = lane & 15, hi = lane >> 4;
    int lx = lo & 7;               // swizzle key

    const bf16_t* qbase = qkvb + (size_t)bm * SEQ * HC;
    const bf16_t* kbase = qkvb + QKV_ONE + (size_t)bm * SEQ * HC;
    const bf16_t* vbase = qkvb + 2 * QKV_ONE + (size_t)bm * HC * SEQ;
    const bf16_t* kfbase = kbase + (size_t)(kf * 256) * HC;   // this block's keys
    const bf16_t* vfbase = vbase + kf * 256;

    __shared__ bf16_t KsF[64 * 64];        // K tile [key][c], swizzled chunks
    __shared__ bf16_t VsF[64 * 64];        // V^T tile [c][key], swizzled chunks
    __shared__ bf16_t PBF[4][64 * 64];     // per-wave P^T [q][k], swizzled chunks
    bf16_t* PBw = PBF[w];

    // staging: thread covers dense LDS chunks e0, e1
    int e0 = tid, e1 = tid + 256;
    int kr0 = e0 >> 3, cs0 = e0 & 7;
    int kr1 = e1 >> 3, cs1 = e1 & 7;
    int kc0 = (cs0 ^ (kr0 & 7)) * 8;
    int kc1 = (cs1 ^ (kr1 & 7)) * 8;

    // prefetch tile 0
    bf16x8 sK0 = *(const bf16x8*)(kfbase + (size_t)kr0 * HC + kc0);
    bf16x8 sK1 = *(const bf16x8*)(kfbase + (size_t)kr1 * HC + kc1);
    bf16x8 sV0 = *(const bf16x8*)(vfbase + (size_t)kr0 * SEQ + kc0);
    bf16x8 sV1 = *(const bf16x8*)(vfbase + (size_t)kr1 * SEQ + kc1);

    // Q B-frags: wave w owns queries f*256 + w*64 .. +63 (q pre-scaled 0.125)
    const bf16_t* qrow = qbase + (size_t)(f * 256 + w * 64 + lo) * HC;
    bf16x8 qf[4][2];
#pragma unroll
    for (int nq = 0; nq < 4; nq++) {
        qf[nq][0] = *(const bf16x8*)(qrow + (size_t)nq * 16 * HC + hi * 8);
        qf[nq][1] = *(const bf16x8*)(qrow + (size_t)nq * 16 * HC + 32 + hi * 8);
    }
    f32x4 o[4][4];
#pragma unroll
    for (int ct = 0; ct < 4; ct++)
#pragma unroll
        for (int nq = 0; nq < 4; nq++) o[ct][nq] = (f32x4){0.f, 0.f, 0.f, 0.f};
    float l4[4] = {0.f, 0.f, 0.f, 0.f};

    for (int kt = 0; kt < 4; kt++) {
        __syncthreads();               // LDS consumed by all waves
        *(bf16x8*)(KsF + e0 * 8) = sK0;
        *(bf16x8*)(KsF + e1 * 8) = sK1;
        *(bf16x8*)(VsF + e0 * 8) = sV0;
        *(bf16x8*)(VsF + e1 * 8) = sV1;
        __syncthreads();               // tiles visible
        if (kt < 3) {
            const bf16_t* kg = kfbase + (size_t)((kt + 1) * 64) * HC;
            const bf16_t* vg = vfbase + (kt + 1) * 64;
            sK0 = *(const bf16x8*)(kg + (size_t)kr0 * HC + kc0);
            sK1 = *(const bf16x8*)(kg + (size_t)kr1 * HC + kc1);
            sV0 = *(const bf16x8*)(vg + (size_t)kr0 * SEQ + kc0);
            sV1 = *(const bf16x8*)(vg + (size_t)kr1 * SEQ + kc1);
        }
        // ---- S^T = K·Q^T, exp, P^T -> LDS
#pragma unroll
        for (int mt = 0; mt < 4; mt++) {
            bf16x8 ka0 = *(const bf16x8*)(KsF + (mt * 16 + lo) * 64 + (hi ^ lx) * 8);
            bf16x8 ka1 = *(const bf16x8*)(KsF + (mt * 16 + lo) * 64 + ((4 + hi) ^ lx) * 8);
#pragma unroll
            for (int nq = 0; nq < 4; nq++) {
                f32x4 s = (f32x4){0.f, 0.f, 0.f, 0.f};
                s = __builtin_amdgcn_mfma_f32_16x16x32_bf16(ka0, qf[nq][0], s, 0, 0, 0);
                s = __builtin_amdgcn_mfma_f32_16x16x32_bf16(ka1, qf[nq][1], s, 0, 0, 0);
                bf16x4 pk;
#pragma unroll
                for (int r = 0; r < 4; r++) {
                    float p = __expf(s[r]);
                    l4[nq] += p;
                    pk[r] = (bf16_t)p;
                }
                *(bf16x4*)(PBw + (nq * 16 + lo) * 64 +
                           (((2 * mt + (hi >> 1)) ^ lx) * 8) + (hi & 1) * 4) = pk;
            }
        }
        // ---- O^T += V^T·P^T (same-wave LDS, in-order)
        bf16x8 pb0[4], pb1[4];
#pragma unroll
        for (int nq = 0; nq < 4; nq++) {
            pb0[nq] = *(const bf16x8*)(PBw + (nq * 16 + lo) * 64 + (hi ^ lx) * 8);
            pb1[nq] = *(const bf16x8*)(PBw + (nq * 16 + lo) * 64 + ((4 + hi) ^ lx) * 8);
        }
#pragma unroll
        for (int ct = 0; ct < 4; ct++) {
            bf16x8 va0 = *(const bf16x8*)(VsF + (ct * 16 + lo) * 64 + (hi ^ lx) * 8);
            bf16x8 va1 = *(const bf16x8*)(VsF + (ct * 16 + lo) * 64 + ((4 + hi) ^ lx) * 8);
#pragma unroll
            for (int nq = 0; nq < 4; nq++) {
                o[ct][nq] = __builtin_amdgcn_mfma_f32_16x16x32_bf16(va0, pb0[nq], o[ct][nq], 0, 0, 0);
                o[ct][nq] = __builtin_amdgcn_mfma_f32_16x16x32_bf16(va1, pb1[nq], o[ct][nq], 0, 0, 0);
            }
        }
    }
    // ---- epilogue: atomic-accumulate partial O and l
#pragma unroll
    for (int nq = 0; nq < 4; nq++) {
        l4[nq] += __shfl_xor(l4[nq], 16, 64);
        l4[nq] += __shfl_xor(l4[nq], 32, 64);
    }
    float* Ob = Oacc + ((size_t)(bm * 8 + f) * 256 + w * 64) * 64;
#pragma unroll
    for (int nq = 0; nq < 4; nq++)
#pragma unroll
        for (int ct = 0; ct < 4; ct++) {
            float* dst = Ob + (size_t)(nq * 16 + lo) * 64 + ct * 16 + hi * 4;
#pragma unroll
            for (int r = 0; r < 4; r++) atomicAdd(dst + r, o[ct][nq][r]);
        }
    if (hi == 0) {
        float* lb = lacc + (size_t)(bm * 8 + f) * 256 + w * 64;
#pragma unroll
        for (int nq = 0; nq < 4; nq++) atomicAdd(lb + nq * 16 + lo, l4[nq]);
    }
}

// ---------------------------------------------------------------------------
// merge: yo[n][p][ci] = Oacc[bm][f][q][c] / lacc[bm][f][q]   (bf16 out)
// 16384 elements per (bm,f) slab -> 64 iterations of 256 threads.
// ---------------------------------------------------------------------------
__global__ __launch_bounds__(256) void va_merge(const float* __restrict__ Oacc,
                                                const float* __restrict__ lacc,
                                                bf16_t* __restrict__ yob) {
    int bm = blockIdx.x;   // 0..23
    int f  = blockIdx.y;   // 0..7
    int head = bm % 12, b = bm / 12;
    const float* Op = Oacc + (size_t)(bm * 8 + f) * 256 * 64;
    const float* lp = lacc + (size_t)(bm * 8 + f) * 256;
    __shared__ float invl[256];
    invl[threadIdx.x] = 1.0f / lp[threadIdx.x];
    __syncthreads();
    bf16_t* dst = yob + (size_t)(b * 8 + f) * NSTRIDE;
#pragma unroll
    for (int j = 0; j < 64; j++) {          // 64*256 = 16384 = 256q x 64c
        int flat = j * 256 + threadIdx.x;
        int q = flat >> 6, c = flat & 63;
        float v = Op[flat] * invl[q];
        dst[(size_t)q * 768 + c * 12 + head] = (bf16_t)v;
    }
}

// ---------------------------------------------------------------------------
// Proj GEMM via MFMA + mp_sum. (unchanged)
// ---------------------------------------------------------------------------
__global__ __launch_bounds__(256, 4) void va_proj_mfma(const bf16_t* __restrict__ Wb,
                                                       const bf16_t* __restrict__ yob,
                                                       const float* __restrict__ x,
                                                       float* __restrict__ out) {
    int n  = blockIdx.z;
    int m0 = blockIdx.y * 128;
    int p0 = blockIdx.x * 128;
    int tid = threadIdx.x;
    int lane = tid & 63, w = tid >> 6;
    int lo = lane & 15, hi = lane >> 4;
    int wm = w >> 1, wn = w & 1;

    const bf16_t* Ap = Wb + (size_t)(m0 + wm * 64 + lo) * 768 + hi * 8;
    const bf16_t* Bp = yob + (size_t)n * NSTRIDE + (size_t)(p0 + wn * 64 + lo) * 768 + hi * 8;

    f32x4 acc[4][4];
#pragma unroll
    for (int mt = 0; mt < 4; mt++)
#pragma unroll
        for (int nt = 0; nt < 4; nt++) acc[mt][nt] = (f32x4){0.f, 0.f, 0.f, 0.f};

    for (int k0 = 0; k0 < 768; k0 += 32) {
        bf16x8 af[4], bf[4];
#pragma unroll
        for (int mt = 0; mt < 4; mt++)
            af[mt] = *(const bf16x8*)(Ap + (size_t)mt * 16 * 768 + k0);
#pragma unroll
        for (int nt = 0; nt < 4; nt++)
            bf[nt] = *(const bf16x8*)(Bp + (size_t)nt * 16 * 768 + k0);
#pragma unroll
        for (int mt = 0; mt < 4; mt++)
#pragma unroll
            for (int nt = 0; nt < 4; nt++)
                acc[mt][nt] = __builtin_amdgcn_mfma_f32_16x16x32_bf16(af[mt], bf[nt], acc[mt][nt], 0, 0, 0);
    }

    const float* xn = x + (size_t)n * NSTRIDE;
    float* on = out + (size_t)n * NSTRIDE;
#pragma unroll
    for (int mt = 0; mt < 4; mt++)
#pragma unroll
        for (int nt = 0; nt < 4; nt++)
#pragma unroll
            for (int r = 0; r < 4; r++) {
                int oo = m0 + wm * 64 + mt * 16 + hi * 4 + r;
                int p  = p0 + wn * 64 + nt * 16 + lo;
                size_t idx = (size_t)oo * 256 + p;
                on[idx] = (xn[idx] * 0.7f + acc[mt][nt][r] * 0.3f) * 1.3130643f;
            }
}

// ---------------------------------------------------------------------------
extern "C" void kernel_launch(void* const* d_in, const int* in_sizes, int n_in,
                              void* d_out, int out_size, void* d_ws, size_t ws_size,
                              hipStream_t stream) {
    const float* x     = (const float*)d_in[0];
    const float* wqkv  = (const float*)d_in[1];
    const float* wproj = (const float*)d_in[2];
    float* out = (float*)d_out;

    // fp32 accumulators first (16B-aligned at ws base)
    float*  Oacc = (float*)d_ws;                              // 24*8*256*64 = 3145728
    float*  lacc = Oacc + (size_t)24 * 8 * 256 * 64;          // 24*8*256    = 49152
    bf16_t* wqkv_nb  = (bf16_t*)(lacc + 49152);               // 2304*768
    bf16_t* wproj_nb = wqkv_nb + (size_t)2304 * 768;          // 768*768
    bf16_t* xt       = wproj_nb + (size_t)768 * 768;          // 16*256*768
    bf16_t* qkvb     = xt + NSTRIDE * 16;                     // 3*QKV_ONE
    bf16_t* yob      = qkvb + 3 * QKV_ONE;                    // QKV_ONE

    int n4 = (3145728 + 49152) / 4;                           // f32x4 count
    va_zero<<<(n4 + 255) / 256, 256, 0, stream>>>((float4*)Oacc, n4);
    va_norm_w<<<3072, 256, 0, stream>>>(wqkv, wproj, wqkv_nb);
    va_x2bf<<<dim3(24, 8, 16), 256, 0, stream>>>(x, xt);
    va_qkv_mfma<<<dim3(2, 18, 16), 256, 0, stream>>>(wqkv_nb, xt, qkvb);
    va_attn<<<dim3(36, 24), 256, 0, stream>>>(qkvb, Oacc, lacc);
    va_merge<<<dim3(24, 8), 256, 0, stream>>>(Oacc, lacc, yob);
    va_proj_mfma<<<dim3(2, 6, 16), 256, 0, stream>>>(wproj_nb, yob, x, out);
}

// Round 10
// 396.100 us; speedup vs baseline: 1.1122x; 1.1122x over previous
//
#include <hip/hip_runtime.h>

typedef __bf16 bf16_t;
typedef __bf16 bf16x4 __attribute__((ext_vector_type(4)));
typedef __bf16 bf16x8 __attribute__((ext_vector_type(8)));
typedef float  f32x4  __attribute__((ext_vector_type(4)));

// Problem constants (setup_inputs: b=2, t=8, C=768, h=w=16)
static constexpr int NHEADS = 12, HC = 64, HW = 256, SEQ = 2048;
static constexpr size_t QKV_ONE = (size_t)2 * NHEADS * SEQ * HC;   // 3145728 elems per q/k/v slab
static constexpr size_t NSTRIDE = 768 * 256;                        // 196608

// ---------------------------------------------------------------------------
// mp_weight for BOTH weights in one launch.
// ---------------------------------------------------------------------------
__global__ __launch_bounds__(256) void va_norm_w(const float* __restrict__ wqkv,
                                                 const float* __restrict__ wproj,
                                                 bf16_t* __restrict__ out) {
    int row = blockIdx.x;
    const float* wr = (row < 2304) ? wqkv + (size_t)row * 768
                                   : wproj + (size_t)(row - 2304) * 768;
    float part = 0.f;
    for (int i = threadIdx.x; i < 768; i += 256) { float v = wr[i]; part += v * v; }
#pragma unroll
    for (int off = 32; off > 0; off >>= 1) part += __shfl_down(part, off, 64);
    __shared__ float red[4];
    if ((threadIdx.x & 63) == 0) red[threadIdx.x >> 6] = part;
    __syncthreads();
    if (threadIdx.x == 0) {
        float s = red[0] + red[1] + red[2] + red[3];
        red[0] = 1.0f / (2.7712813e-3f + sqrtf(s));   // EPS*sqrt(768) + ||w||
    }
    __syncthreads();
    float sc = red[0];
    for (int i = threadIdx.x; i < 768; i += 256)
        out[(size_t)row * 768 + i] = (bf16_t)(wr[i] * sc);
}

// ---------------------------------------------------------------------------
// x fp32 [n][768 c][256 p]  ->  xt bf16 [n][256 p][768 c]
// ---------------------------------------------------------------------------
__global__ __launch_bounds__(256) void va_x2bf(const float* __restrict__ x,
                                               bf16_t* __restrict__ xt) {
    int n  = blockIdx.z;
    int c0 = blockIdx.x * 32;
    int p0 = blockIdx.y * 32;
    __shared__ float sm[32][33];
    int tx = threadIdx.x & 31, ty = threadIdx.x >> 5;
    const float* xp = x + (size_t)n * NSTRIDE;
#pragma unroll
    for (int i = 0; i < 4; i++)
        sm[ty + i * 8][tx] = xp[(size_t)(c0 + ty + i * 8) * 256 + p0 + tx];
    __syncthreads();
    bf16_t* xo = xt + (size_t)n * NSTRIDE;
#pragma unroll
    for (int i = 0; i < 4; i++)
        xo[(size_t)(p0 + ty + i * 8) * 768 + c0 + tx] = (bf16_t)sm[tx][ty + i * 8];
}

// ---------------------------------------------------------------------------
// QKV GEMM via MFMA, RoPE + q-scale fused in epilogue. (unchanged)
// ---------------------------------------------------------------------------
__global__ __launch_bounds__(256, 4) void va_qkv_mfma(const bf16_t* __restrict__ Wb,
                                                      const bf16_t* __restrict__ xt,
                                                      bf16_t* __restrict__ qkvb) {
    int n  = blockIdx.z;
    int m0 = blockIdx.y * 128;
    int p0 = blockIdx.x * 128;
    int tid = threadIdx.x;
    int lane = tid & 63, w = tid >> 6;
    int lo = lane & 15, hi = lane >> 4;
    int wm = w >> 1, wn = w & 1;

    const bf16_t* Ap = Wb + (size_t)(m0 + wm * 64 + lo) * 768 + hi * 8;
    const bf16_t* Bp = xt + (size_t)n * NSTRIDE + (size_t)(p0 + wn * 64 + lo) * 768 + hi * 8;

    f32x4 acc[4][4];
#pragma unroll
    for (int mt = 0; mt < 4; mt++)
#pragma unroll
        for (int nt = 0; nt < 4; nt++) acc[mt][nt] = (f32x4){0.f, 0.f, 0.f, 0.f};

    for (int k0 = 0; k0 < 768; k0 += 32) {
        bf16x8 af[4], bf[4];
#pragma unroll
        for (int mt = 0; mt < 4; mt++)
            af[mt] = *(const bf16x8*)(Ap + (size_t)mt * 16 * 768 + k0);
#pragma unroll
        for (int nt = 0; nt < 4; nt++)
            bf[nt] = *(const bf16x8*)(Bp + (size_t)nt * 16 * 768 + k0);
#pragma unroll
        for (int mt = 0; mt < 4; mt++)
#pragma unroll
            for (int nt = 0; nt < 4; nt++)
                acc[mt][nt] = __builtin_amdgcn_mfma_f32_16x16x32_bf16(af[mt], bf[nt], acc[mt][nt], 0, 0, 0);
    }

    int head_global = (m0 + wm * 64) >> 6;
    int qkv_idx = head_global / 12;
    int head    = head_global % 12;
    int b = n >> 3, tt = n & 7;
    int bm = b * 12 + head;
    if (qkv_idx < 2) {
        float qsc = (qkv_idx == 0) ? 0.125f : 1.0f;
        float ttf = (float)tt;
#pragma unroll
        for (int mt = 0; mt < 2; mt++)
#pragma unroll
            for (int r = 0; r < 4; r++) {
                int j = mt * 16 + hi * 4 + r;
                float ang = ttf * __expf(-(float)j * 0.2878231366242557f);
                float cs = __cosf(ang), sn = __sinf(ang);
#pragma unroll
                for (int nt = 0; nt < 4; nt++) {
                    float x1 = acc[mt][nt][r], x2 = acc[mt + 2][nt][r];
                    acc[mt][nt][r]     = (x1 * cs - x2 * sn) * qsc;
                    acc[mt + 2][nt][r] = (x1 * sn + x2 * cs) * qsc;
                }
            }
        bf16_t* dst = qkvb + (size_t)qkv_idx * QKV_ONE + ((size_t)bm * SEQ + (size_t)tt * HW) * HC;
#pragma unroll
        for (int mt = 0; mt < 4; mt++)
#pragma unroll
            for (int nt = 0; nt < 4; nt++)
#pragma unroll
                for (int r = 0; r < 4; r++) {
                    int cc = mt * 16 + hi * 4 + r;
                    int p  = p0 + wn * 64 + nt * 16 + lo;
                    dst[(size_t)p * HC + cc] = (bf16_t)acc[mt][nt][r];
                }
    } else {
        bf16_t* dst = qkvb + 2 * QKV_ONE + (size_t)bm * HC * SEQ + (size_t)tt * HW;
#pragma unroll
        for (int mt = 0; mt < 4; mt++)
#pragma unroll
            for (int nt = 0; nt < 4; nt++)
#pragma unroll
                for (int r = 0; r < 4; r++) {
                    int cc = mt * 16 + hi * 4 + r;
                    int p  = p0 + wn * 64 + nt * 16 + lo;
                    dst[(size_t)cc * SEQ + p] = (bf16_t)acc[mt][nt][r];
                }
    }
}

// ---------------------------------------------------------------------------
// MFMA flash attention v5: block-level split-K with PRIVATE partial slabs
// (round 9's atomics caused 362 MB of memory-side RMW traffic — plain
// once-written stores instead). Grid = (36 (f,kf) pairs, 24 bm); every block
// identical: 4 key tiles x 256 queries, 4 waves sharing LDS-staged K/V.
// Partial O (fp32, dwordx4 stores) + l go to Opart/lpart[bm*36+pidx];
// va_merge sums the <=8 slabs per (bm,f) and normalizes.
// ---------------------------------------------------------------------------
__global__ __launch_bounds__(256, 3) void va_attn(const bf16_t* __restrict__ qkvb,
                                                  float* __restrict__ Opart,
                                                  float* __restrict__ lpart) {
    int pidx = blockIdx.x;         // 0..35  -> (f, kf<=f)
    int bm   = blockIdx.y;         // 0..23
    int f = 0;
    while ((f + 1) * (f + 2) / 2 <= pidx) f++;
    int kf = pidx - f * (f + 1) / 2;

    int tid = threadIdx.x;
    int w = tid >> 6, lane = tid & 63;
    int lo = lane & 15, hi = lane >> 4;
    int lx = lo & 7;               // swizzle key

    const bf16_t* qbase = qkvb + (size_t)bm * SEQ * HC;
    const bf16_t* kbase = qkvb + QKV_ONE + (size_t)bm * SEQ * HC;
    const bf16_t* vbase = qkvb + 2 * QKV_ONE + (size_t)bm * HC * SEQ;
    const bf16_t* kfbase = kbase + (size_t)(kf * 256) * HC;   // this block's keys
    const bf16_t* vfbase = vbase + kf * 256;

    __shared__ bf16_t KsF[64 * 64];        // K tile [key][c], swizzled chunks
    __shared__ bf16_t VsF[64 * 64];        // V^T tile [c][key], swizzled chunks
    __shared__ bf16_t PBF[4][64 * 64];     // per-wave P^T [q][k], swizzled chunks
    bf16_t* PBw = PBF[w];

    // staging: thread covers dense LDS chunks e0, e1
    int e0 = tid, e1 = tid + 256;
    int kr0 = e0 >> 3, cs0 = e0 & 7;
    int kr1 = e1 >> 3, cs1 = e1 & 7;
    int kc0 = (cs0 ^ (kr0 & 7)) * 8;
    int kc1 = (cs1 ^ (kr1 & 7)) * 8;

    // prefetch tile 0
    bf16x8 sK0 = *(const bf16x8*)(kfbase + (size_t)kr0 * HC + kc0);
    bf16x8 sK1 = *(const bf16x8*)(kfbase + (size_t)kr1 * HC + kc1);
    bf16x8 sV0 = *(const bf16x8*)(vfbase + (size_t)kr0 * SEQ + kc0);
    bf16x8 sV1 = *(const bf16x8*)(vfbase + (size_t)kr1 * SEQ + kc1);

    // Q B-frags: wave w owns queries f*256 + w*64 .. +63 (q pre-scaled 0.125)
    const bf16_t* qrow = qbase + (size_t)(f * 256 + w * 64 + lo) * HC;
    bf16x8 qf[4][2];
#pragma unroll
    for (int nq = 0; nq < 4; nq++) {
        qf[nq][0] = *(const bf16x8*)(qrow + (size_t)nq * 16 * HC + hi * 8);
        qf[nq][1] = *(const bf16x8*)(qrow + (size_t)nq * 16 * HC + 32 + hi * 8);
    }
    f32x4 o[4][4];
#pragma unroll
    for (int ct = 0; ct < 4; ct++)
#pragma unroll
        for (int nq = 0; nq < 4; nq++) o[ct][nq] = (f32x4){0.f, 0.f, 0.f, 0.f};
    float l4[4] = {0.f, 0.f, 0.f, 0.f};

    for (int kt = 0; kt < 4; kt++) {
        __syncthreads();               // LDS consumed by all waves
        *(bf16x8*)(KsF + e0 * 8) = sK0;
        *(bf16x8*)(KsF + e1 * 8) = sK1;
        *(bf16x8*)(VsF + e0 * 8) = sV0;
        *(bf16x8*)(VsF + e1 * 8) = sV1;
        __syncthreads();               // tiles visible
        if (kt < 3) {
            const bf16_t* kg = kfbase + (size_t)((kt + 1) * 64) * HC;
            const bf16_t* vg = vfbase + (kt + 1) * 64;
            sK0 = *(const bf16x8*)(kg + (size_t)kr0 * HC + kc0);
            sK1 = *(const bf16x8*)(kg + (size_t)kr1 * HC + kc1);
            sV0 = *(const bf16x8*)(vg + (size_t)kr0 * SEQ + kc0);
            sV1 = *(const bf16x8*)(vg + (size_t)kr1 * SEQ + kc1);
        }
        // ---- S^T = K·Q^T, exp, P^T -> LDS
#pragma unroll
        for (int mt = 0; mt < 4; mt++) {
            bf16x8 ka0 = *(const bf16x8*)(KsF + (mt * 16 + lo) * 64 + (hi ^ lx) * 8);
            bf16x8 ka1 = *(const bf16x8*)(KsF + (mt * 16 + lo) * 64 + ((4 + hi) ^ lx) * 8);
#pragma unroll
            for (int nq = 0; nq < 4; nq++) {
                f32x4 s = (f32x4){0.f, 0.f, 0.f, 0.f};
                s = __builtin_amdgcn_mfma_f32_16x16x32_bf16(ka0, qf[nq][0], s, 0, 0, 0);
                s = __builtin_amdgcn_mfma_f32_16x16x32_bf16(ka1, qf[nq][1], s, 0, 0, 0);
                bf16x4 pk;
#pragma unroll
                for (int r = 0; r < 4; r++) {
                    float p = __expf(s[r]);
                    l4[nq] += p;
                    pk[r] = (bf16_t)p;
                }
                *(bf16x4*)(PBw + (nq * 16 + lo) * 64 +
                           (((2 * mt + (hi >> 1)) ^ lx) * 8) + (hi & 1) * 4) = pk;
            }
        }
        // ---- O^T += V^T·P^T (same-wave LDS, in-order)
        bf16x8 pb0[4], pb1[4];
#pragma unroll
        for (int nq = 0; nq < 4; nq++) {
            pb0[nq] = *(const bf16x8*)(PBw + (nq * 16 + lo) * 64 + (hi ^ lx) * 8);
            pb1[nq] = *(const bf16x8*)(PBw + (nq * 16 + lo) * 64 + ((4 + hi) ^ lx) * 8);
        }
#pragma unroll
        for (int ct = 0; ct < 4; ct++) {
            bf16x8 va0 = *(const bf16x8*)(VsF + (ct * 16 + lo) * 64 + (hi ^ lx) * 8);
            bf16x8 va1 = *(const bf16x8*)(VsF + (ct * 16 + lo) * 64 + ((4 + hi) ^ lx) * 8);
#pragma unroll
            for (int nq = 0; nq < 4; nq++) {
                o[ct][nq] = __builtin_amdgcn_mfma_f32_16x16x32_bf16(va0, pb0[nq], o[ct][nq], 0, 0, 0);
                o[ct][nq] = __builtin_amdgcn_mfma_f32_16x16x32_bf16(va1, pb1[nq], o[ct][nq], 0, 0, 0);
            }
        }
    }
    // ---- epilogue: plain vectorized stores to this block's private slab
#pragma unroll
    for (int nq = 0; nq < 4; nq++) {
        l4[nq] += __shfl_xor(l4[nq], 16, 64);
        l4[nq] += __shfl_xor(l4[nq], 32, 64);
    }
    float* Ob = Opart + ((size_t)(bm * 36 + pidx) * 256 + w * 64) * 64;
#pragma unroll
    for (int nq = 0; nq < 4; nq++)
#pragma unroll
        for (int ct = 0; ct < 4; ct++)
            *(f32x4*)(Ob + (size_t)(nq * 16 + lo) * 64 + ct * 16 + hi * 4) = o[ct][nq];
    if (hi == 0) {
        float* lb = lpart + (size_t)(bm * 36 + pidx) * 256 + w * 64;
#pragma unroll
        for (int nq = 0; nq < 4; nq++) lb[nq * 16 + lo] = l4[nq];
    }
}

// ---------------------------------------------------------------------------
// merge: yo[n][p][ci] = sum_kf Opart[bm][f,kf][q][c] / sum_kf lpart[...][q]
// ---------------------------------------------------------------------------
__global__ __launch_bounds__(256) void va_merge(const float* __restrict__ Opart,
                                                const float* __restrict__ lpart,
                                                bf16_t* __restrict__ yob) {
    int bm = blockIdx.x;   // 0..23
    int f  = blockIdx.y;   // 0..7
    int head = bm % 12, b = bm / 12;
    int sbase = bm * 36 + f * (f + 1) / 2;      // first kf slab for (bm,f)
    const float* lp = lpart + (size_t)sbase * 256;
    __shared__ float invl[256];
    float ls = 0.f;
    for (int kf = 0; kf <= f; kf++) ls += lp[kf * 256 + threadIdx.x];
    invl[threadIdx.x] = 1.0f / ls;
    __syncthreads();
    const float* Ob = Opart + (size_t)sbase * 16384;
    bf16_t* dst = yob + (size_t)(b * 8 + f) * NSTRIDE;
    for (int j = 0; j < 64; j++) {              // 64*256 = 16384 = 256q x 64c
        int flat = j * 256 + threadIdx.x;
        float v = 0.f;
        for (int kf = 0; kf <= f; kf++) v += Ob[(size_t)kf * 16384 + flat];
        int q = flat >> 6, c = flat & 63;
        dst[(size_t)q * 768 + c * 12 + head] = (bf16_t)(v * invl[q]);
    }
}

// ---------------------------------------------------------------------------
// Proj GEMM via MFMA + mp_sum. (unchanged)
// ---------------------------------------------------------------------------
__global__ __launch_bounds__(256, 4) void va_proj_mfma(const bf16_t* __restrict__ Wb,
                                                       const bf16_t* __restrict__ yob,
                                                       const float* __restrict__ x,
                                                       float* __restrict__ out) {
    int n  = blockIdx.z;
    int m0 = blockIdx.y * 128;
    int p0 = blockIdx.x * 128;
    int tid = threadIdx.x;
    int lane = tid & 63, w = tid >> 6;
    int lo = lane & 15, hi = lane >> 4;
    int wm = w >> 1, wn = w & 1;

    const bf16_t* Ap = Wb + (size_t)(m0 + wm * 64 + lo) * 768 + hi * 8;
    const bf16_t* Bp = yob + (size_t)n * NSTRIDE + (size_t)(p0 + wn * 64 + lo) * 768 + hi * 8;

    f32x4 acc[4][4];
#pragma unroll
    for (int mt = 0; mt < 4; mt++)
#pragma unroll
        for (int nt = 0; nt < 4; nt++) acc[mt][nt] = (f32x4){0.f, 0.f, 0.f, 0.f};

    for (int k0 = 0; k0 < 768; k0 += 32) {
        bf16x8 af[4], bf[4];
#pragma unroll
        for (int mt = 0; mt < 4; mt++)
            af[mt] = *(const bf16x8*)(Ap + (size_t)mt * 16 * 768 + k0);
#pragma unroll
        for (int nt = 0; nt < 4; nt++)
            bf[nt] = *(const bf16x8*)(Bp + (size_t)nt * 16 * 768 + k0);
#pragma unroll
        for (int mt = 0; mt < 4; mt++)
#pragma unroll
            for (int nt = 0; nt < 4; nt++)
                acc[mt][nt] = __builtin_amdgcn_mfma_f32_16x16x32_bf16(af[mt], bf[nt], acc[mt][nt], 0, 0, 0);
    }

    const float* xn = x + (size_t)n * NSTRIDE;
    float* on = out + (size_t)n * NSTRIDE;
#pragma unroll
    for (int mt = 0; mt < 4; mt++)
#pragma unroll
        for (int nt = 0; nt < 4; nt++)
#pragma unroll
            for (int r = 0; r < 4; r++) {
                int oo = m0 + wm * 64 + mt * 16 + hi * 4 + r;
                int p  = p0 + wn * 64 + nt * 16 + lo;
                size_t idx = (size_t)oo * 256 + p;
                on[idx] = (xn[idx] * 0.7f + acc[mt][nt][r] * 0.3f) * 1.3130643f;
            }
}

// ---------------------------------------------------------------------------
extern "C" void kernel_launch(void* const* d_in, const int* in_sizes, int n_in,
                              void* d_out, int out_size, void* d_ws, size_t ws_size,
                              hipStream_t stream) {
    const float* x     = (const float*)d_in[0];
    const float* wqkv  = (const float*)d_in[1];
    const float* wproj = (const float*)d_in[2];
    float* out = (float*)d_out;

    // fp32 partial slabs first (16B-aligned at ws base); each written exactly
    // once per launch by its owning block -> no zero-init needed.
    float*  Opart = (float*)d_ws;                             // 24*36*16384 = 14155776
    float*  lpart = Opart + (size_t)24 * 36 * 16384;          // 24*36*256   = 221184
    bf16_t* wqkv_nb  = (bf16_t*)(lpart + (size_t)24 * 36 * 256);
    bf16_t* wproj_nb = wqkv_nb + (size_t)2304 * 768;
    bf16_t* xt       = wproj_nb + (size_t)768 * 768;
    bf16_t* qkvb     = xt + NSTRIDE * 16;
    bf16_t* yob      = qkvb + 3 * QKV_ONE;

    va_norm_w<<<3072, 256, 0, stream>>>(wqkv, wproj, wqkv_nb);
    va_x2bf<<<dim3(24, 8, 16), 256, 0, stream>>>(x, xt);
    va_qkv_mfma<<<dim3(2, 18, 16), 256, 0, stream>>>(wqkv_nb, xt, qkvb);
    va_attn<<<dim3(36, 24), 256, 0, stream>>>(qkvb, Opart, lpart);
    va_merge<<<dim3(24, 8), 256, 0, stream>>>(Opart, lpart, yob);
    va_proj_mfma<<<dim3(2, 6, 16), 256, 0, stream>>>(wproj_nb, yob, x, out);
}

// Round 11
// 275.421 us; speedup vs baseline: 1.5995x; 1.4382x over previous
//
#include <hip/hip_runtime.h>

typedef __bf16 bf16_t;
typedef __bf16 bf16x4 __attribute__((ext_vector_type(4)));
typedef __bf16 bf16x8 __attribute__((ext_vector_type(8)));
typedef float  f32x4  __attribute__((ext_vector_type(4)));

// Problem constants (setup_inputs: b=2, t=8, C=768, h=w=16)
static constexpr int NHEADS = 12, HC = 64, HW = 256, SEQ = 2048;
static constexpr size_t QKV_ONE = (size_t)2 * NHEADS * SEQ * HC;   // 3145728 elems per q/k/v slab
static constexpr size_t NSTRIDE = 768 * 256;                        // 196608

// ---------------------------------------------------------------------------
// mp_weight for BOTH weights in one launch. wproj rows additionally get their
// COLUMNS PERMUTED: stored index j = head*64 + c for source i = c*12 + head,
// so yo can live in natural [head][c] channel order (dense merge writes) while
// proj GEMM stays mathematically identical.
// ---------------------------------------------------------------------------
__global__ __launch_bounds__(256) void va_norm_w(const float* __restrict__ wqkv,
                                                 const float* __restrict__ wproj,
                                                 bf16_t* __restrict__ out) {
    int row = blockIdx.x;
    bool is_proj = (row >= 2304);
    const float* wr = is_proj ? wproj + (size_t)(row - 2304) * 768
                              : wqkv + (size_t)row * 768;
    float part = 0.f;
    for (int i = threadIdx.x; i < 768; i += 256) { float v = wr[i]; part += v * v; }
#pragma unroll
    for (int off = 32; off > 0; off >>= 1) part += __shfl_down(part, off, 64);
    __shared__ float red[4];
    if ((threadIdx.x & 63) == 0) red[threadIdx.x >> 6] = part;
    __syncthreads();
    if (threadIdx.x == 0) {
        float s = red[0] + red[1] + red[2] + red[3];
        red[0] = 1.0f / (2.7712813e-3f + sqrtf(s));   // EPS*sqrt(768) + ||w||
    }
    __syncthreads();
    float sc = red[0];
    for (int i = threadIdx.x; i < 768; i += 256) {
        int j = is_proj ? ((i % 12) * 64 + i / 12) : i;   // column permute for wproj
        out[(size_t)row * 768 + j] = (bf16_t)(wr[i] * sc);
    }
}

// ---------------------------------------------------------------------------
// x fp32 [n][768 c][256 p]  ->  xt bf16 [n][256 p][768 c]
// ---------------------------------------------------------------------------
__global__ __launch_bounds__(256) void va_x2bf(const float* __restrict__ x,
                                               bf16_t* __restrict__ xt) {
    int n  = blockIdx.z;
    int c0 = blockIdx.x * 32;
    int p0 = blockIdx.y * 32;
    __shared__ float sm[32][33];
    int tx = threadIdx.x & 31, ty = threadIdx.x >> 5;
    const float* xp = x + (size_t)n * NSTRIDE;
#pragma unroll
    for (int i = 0; i < 4; i++)
        sm[ty + i * 8][tx] = xp[(size_t)(c0 + ty + i * 8) * 256 + p0 + tx];
    __syncthreads();
    bf16_t* xo = xt + (size_t)n * NSTRIDE;
#pragma unroll
    for (int i = 0; i < 4; i++)
        xo[(size_t)(p0 + ty + i * 8) * 768 + c0 + tx] = (bf16_t)sm[tx][ty + i * 8];
}

// ---------------------------------------------------------------------------
// QKV GEMM via MFMA, RoPE + q-scale fused in epilogue. (unchanged)
// ---------------------------------------------------------------------------
__global__ __launch_bounds__(256, 4) void va_qkv_mfma(const bf16_t* __restrict__ Wb,
                                                      const bf16_t* __restrict__ xt,
                                                      bf16_t* __restrict__ qkvb) {
    int n  = blockIdx.z;
    int m0 = blockIdx.y * 128;
    int p0 = blockIdx.x * 128;
    int tid = threadIdx.x;
    int lane = tid & 63, w = tid >> 6;
    int lo = lane & 15, hi = lane >> 4;
    int wm = w >> 1, wn = w & 1;

    const bf16_t* Ap = Wb + (size_t)(m0 + wm * 64 + lo) * 768 + hi * 8;
    const bf16_t* Bp = xt + (size_t)n * NSTRIDE + (size_t)(p0 + wn * 64 + lo) * 768 + hi * 8;

    f32x4 acc[4][4];
#pragma unroll
    for (int mt = 0; mt < 4; mt++)
#pragma unroll
        for (int nt = 0; nt < 4; nt++) acc[mt][nt] = (f32x4){0.f, 0.f, 0.f, 0.f};

    for (int k0 = 0; k0 < 768; k0 += 32) {
        bf16x8 af[4], bf[4];
#pragma unroll
        for (int mt = 0; mt < 4; mt++)
            af[mt] = *(const bf16x8*)(Ap + (size_t)mt * 16 * 768 + k0);
#pragma unroll
        for (int nt = 0; nt < 4; nt++)
            bf[nt] = *(const bf16x8*)(Bp + (size_t)nt * 16 * 768 + k0);
#pragma unroll
        for (int mt = 0; mt < 4; mt++)
#pragma unroll
            for (int nt = 0; nt < 4; nt++)
                acc[mt][nt] = __builtin_amdgcn_mfma_f32_16x16x32_bf16(af[mt], bf[nt], acc[mt][nt], 0, 0, 0);
    }

    int head_global = (m0 + wm * 64) >> 6;
    int qkv_idx = head_global / 12;
    int head    = head_global % 12;
    int b = n >> 3, tt = n & 7;
    int bm = b * 12 + head;
    if (qkv_idx < 2) {
        float qsc = (qkv_idx == 0) ? 0.125f : 1.0f;
        float ttf = (float)tt;
#pragma unroll
        for (int mt = 0; mt < 2; mt++)
#pragma unroll
            for (int r = 0; r < 4; r++) {
                int j = mt * 16 + hi * 4 + r;
                float ang = ttf * __expf(-(float)j * 0.2878231366242557f);
                float cs = __cosf(ang), sn = __sinf(ang);
#pragma unroll
                for (int nt = 0; nt < 4; nt++) {
                    float x1 = acc[mt][nt][r], x2 = acc[mt + 2][nt][r];
                    acc[mt][nt][r]     = (x1 * cs - x2 * sn) * qsc;
                    acc[mt + 2][nt][r] = (x1 * sn + x2 * cs) * qsc;
                }
            }
        bf16_t* dst = qkvb + (size_t)qkv_idx * QKV_ONE + ((size_t)bm * SEQ + (size_t)tt * HW) * HC;
#pragma unroll
        for (int mt = 0; mt < 4; mt++)
#pragma unroll
            for (int nt = 0; nt < 4; nt++)
#pragma unroll
                for (int r = 0; r < 4; r++) {
                    int cc = mt * 16 + hi * 4 + r;
                    int p  = p0 + wn * 64 + nt * 16 + lo;
                    dst[(size_t)p * HC + cc] = (bf16_t)acc[mt][nt][r];
                }
    } else {
        bf16_t* dst = qkvb + 2 * QKV_ONE + (size_t)bm * HC * SEQ + (size_t)tt * HW;
#pragma unroll
        for (int mt = 0; mt < 4; mt++)
#pragma unroll
            for (int nt = 0; nt < 4; nt++)
#pragma unroll
                for (int r = 0; r < 4; r++) {
                    int cc = mt * 16 + hi * 4 + r;
                    int p  = p0 + wn * 64 + nt * 16 + lo;
                    dst[(size_t)cc * SEQ + p] = (bf16_t)acc[mt][nt][r];
                }
    }
}

// ---------------------------------------------------------------------------
// MFMA flash attention v5: block-level split-K with private partial slabs.
// (unchanged from round 10)
// ---------------------------------------------------------------------------
__global__ __launch_bounds__(256, 3) void va_attn(const bf16_t* __restrict__ qkvb,
                                                  float* __restrict__ Opart,
                                                  float* __restrict__ lpart) {
    int pidx = blockIdx.x;         // 0..35  -> (f, kf<=f)
    int bm   = blockIdx.y;         // 0..23
    int f = 0;
    while ((f + 1) * (f + 2) / 2 <= pidx) f++;
    int kf = pidx - f * (f + 1) / 2;

    int tid = threadIdx.x;
    int w = tid >> 6, lane = tid & 63;
    int lo = lane & 15, hi = lane >> 4;
    int lx = lo & 7;               // swizzle key

    const bf16_t* qbase = qkvb + (size_t)bm * SEQ * HC;
    const bf16_t* kbase = qkvb + QKV_ONE + (size_t)bm * SEQ * HC;
    const bf16_t* vbase = qkvb + 2 * QKV_ONE + (size_t)bm * HC * SEQ;
    const bf16_t* kfbase = kbase + (size_t)(kf * 256) * HC;
    const bf16_t* vfbase = vbase + kf * 256;

    __shared__ bf16_t KsF[64 * 64];
    __shared__ bf16_t VsF[64 * 64];
    __shared__ bf16_t PBF[4][64 * 64];
    bf16_t* PBw = PBF[w];

    int e0 = tid, e1 = tid + 256;
    int kr0 = e0 >> 3, cs0 = e0 & 7;
    int kr1 = e1 >> 3, cs1 = e1 & 7;
    int kc0 = (cs0 ^ (kr0 & 7)) * 8;
    int kc1 = (cs1 ^ (kr1 & 7)) * 8;

    bf16x8 sK0 = *(const bf16x8*)(kfbase + (size_t)kr0 * HC + kc0);
    bf16x8 sK1 = *(const bf16x8*)(kfbase + (size_t)kr1 * HC + kc1);
    bf16x8 sV0 = *(const bf16x8*)(vfbase + (size_t)kr0 * SEQ + kc0);
    bf16x8 sV1 = *(const bf16x8*)(vfbase + (size_t)kr1 * SEQ + kc1);

    const bf16_t* qrow = qbase + (size_t)(f * 256 + w * 64 + lo) * HC;
    bf16x8 qf[4][2];
#pragma unroll
    for (int nq = 0; nq < 4; nq++) {
        qf[nq][0] = *(const bf16x8*)(qrow + (size_t)nq * 16 * HC + hi * 8);
        qf[nq][1] = *(const bf16x8*)(qrow + (size_t)nq * 16 * HC + 32 + hi * 8);
    }
    f32x4 o[4][4];
#pragma unroll
    for (int ct = 0; ct < 4; ct++)
#pragma unroll
        for (int nq = 0; nq < 4; nq++) o[ct][nq] = (f32x4){0.f, 0.f, 0.f, 0.f};
    float l4[4] = {0.f, 0.f, 0.f, 0.f};

    for (int kt = 0; kt < 4; kt++) {
        __syncthreads();
        *(bf16x8*)(KsF + e0 * 8) = sK0;
        *(bf16x8*)(KsF + e1 * 8) = sK1;
        *(bf16x8*)(VsF + e0 * 8) = sV0;
        *(bf16x8*)(VsF + e1 * 8) = sV1;
        __syncthreads();
        if (kt < 3) {
            const bf16_t* kg = kfbase + (size_t)((kt + 1) * 64) * HC;
            const bf16_t* vg = vfbase + (kt + 1) * 64;
            sK0 = *(const bf16x8*)(kg + (size_t)kr0 * HC + kc0);
            sK1 = *(const bf16x8*)(kg + (size_t)kr1 * HC + kc1);
            sV0 = *(const bf16x8*)(vg + (size_t)kr0 * SEQ + kc0);
            sV1 = *(const bf16x8*)(vg + (size_t)kr1 * SEQ + kc1);
        }
#pragma unroll
        for (int mt = 0; mt < 4; mt++) {
            bf16x8 ka0 = *(const bf16x8*)(KsF + (mt * 16 + lo) * 64 + (hi ^ lx) * 8);
            bf16x8 ka1 = *(const bf16x8*)(KsF + (mt * 16 + lo) * 64 + ((4 + hi) ^ lx) * 8);
#pragma unroll
            for (int nq = 0; nq < 4; nq++) {
                f32x4 s = (f32x4){0.f, 0.f, 0.f, 0.f};
                s = __builtin_amdgcn_mfma_f32_16x16x32_bf16(ka0, qf[nq][0], s, 0, 0, 0);
                s = __builtin_amdgcn_mfma_f32_16x16x32_bf16(ka1, qf[nq][1], s, 0, 0, 0);
                bf16x4 pk;
#pragma unroll
                for (int r = 0; r < 4; r++) {
                    float p = __expf(s[r]);
                    l4[nq] += p;
                    pk[r] = (bf16_t)p;
                }
                *(bf16x4*)(PBw + (nq * 16 + lo) * 64 +
                           (((2 * mt + (hi >> 1)) ^ lx) * 8) + (hi & 1) * 4) = pk;
            }
        }
        bf16x8 pb0[4], pb1[4];
#pragma unroll
        for (int nq = 0; nq < 4; nq++) {
            pb0[nq] = *(const bf16x8*)(PBw + (nq * 16 + lo) * 64 + (hi ^ lx) * 8);
            pb1[nq] = *(const bf16x8*)(PBw + (nq * 16 + lo) * 64 + ((4 + hi) ^ lx) * 8);
        }
#pragma unroll
        for (int ct = 0; ct < 4; ct++) {
            bf16x8 va0 = *(const bf16x8*)(VsF + (ct * 16 + lo) * 64 + (hi ^ lx) * 8);
            bf16x8 va1 = *(const bf16x8*)(VsF + (ct * 16 + lo) * 64 + ((4 + hi) ^ lx) * 8);
#pragma unroll
            for (int nq = 0; nq < 4; nq++) {
                o[ct][nq] = __builtin_amdgcn_mfma_f32_16x16x32_bf16(va0, pb0[nq], o[ct][nq], 0, 0, 0);
                o[ct][nq] = __builtin_amdgcn_mfma_f32_16x16x32_bf16(va1, pb1[nq], o[ct][nq], 0, 0, 0);
            }
        }
    }
#pragma unroll
    for (int nq = 0; nq < 4; nq++) {
        l4[nq] += __shfl_xor(l4[nq], 16, 64);
        l4[nq] += __shfl_xor(l4[nq], 32, 64);
    }
    float* Ob = Opart + ((size_t)(bm * 36 + pidx) * 256 + w * 64) * 64;
#pragma unroll
    for (int nq = 0; nq < 4; nq++)
#pragma unroll
        for (int ct = 0; ct < 4; ct++)
            *(f32x4*)(Ob + (size_t)(nq * 16 + lo) * 64 + ct * 16 + hi * 4) = o[ct][nq];
    if (hi == 0) {
        float* lb = lpart + (size_t)(bm * 36 + pidx) * 256 + w * 64;
#pragma unroll
        for (int nq = 0; nq < 4; nq++) lb[nq * 16 + lo] = l4[nq];
    }
}

// ---------------------------------------------------------------------------
// merge v2: flat, one f32x4 per thread, fully coalesced.
// yo channel order is now head*64+c (wproj columns pre-permuted to match), so
// writes are dense bf16x4. 786432 chunks = 3072 blocks x 256 threads.
// ---------------------------------------------------------------------------
__global__ __launch_bounds__(256) void va_merge(const float* __restrict__ Opart,
                                                const float* __restrict__ lpart,
                                                bf16_t* __restrict__ yob) {
    int t = blockIdx.x * 256 + threadIdx.x;   // f32x4 chunk id, < 786432
    int bm   = t >> 15;                       // 0..23
    int rem  = t & 32767;
    int f    = rem >> 12;                     // 0..7
    int rem2 = rem & 4095;
    int q    = rem2 >> 4;                     // 0..255
    int c4   = rem2 & 15;                     // 16-byte chunk within 64 c
    int sbase = bm * 36 + f * (f + 1) / 2;

    float lsum = 0.f;
    for (int kf = 0; kf <= f; kf++)
        lsum += lpart[(size_t)(sbase + kf) * 256 + q];
    f32x4 v = (f32x4){0.f, 0.f, 0.f, 0.f};
    const float* Ob = Opart + (size_t)sbase * 16384 + (size_t)q * 64 + c4 * 4;
    for (int kf = 0; kf <= f; kf++)
        v += *(const f32x4*)(Ob + (size_t)kf * 16384);

    float invl = 1.0f / lsum;
    int head = bm % 12, b = bm / 12;
    bf16x4 o4;
#pragma unroll
    for (int r = 0; r < 4; r++) o4[r] = (bf16_t)(v[r] * invl);
    *(bf16x4*)(yob + (size_t)(b * 8 + f) * NSTRIDE + (size_t)q * 768 + head * 64 + c4 * 4) = o4;
}

// ---------------------------------------------------------------------------
// Proj GEMM via MFMA + mp_sum. (unchanged; weights column-permuted upstream)
// ---------------------------------------------------------------------------
__global__ __launch_bounds__(256, 4) void va_proj_mfma(const bf16_t* __restrict__ Wb,
                                                       const bf16_t* __restrict__ yob,
                                                       const float* __restrict__ x,
                                                       float* __restrict__ out) {
    int n  = blockIdx.z;
    int m0 = blockIdx.y * 128;
    int p0 = blockIdx.x * 128;
    int tid = threadIdx.x;
    int lane = tid & 63, w = tid >> 6;
    int lo = lane & 15, hi = lane >> 4;
    int wm = w >> 1, wn = w & 1;

    const bf16_t* Ap = Wb + (size_t)(m0 + wm * 64 + lo) * 768 + hi * 8;
    const bf16_t* Bp = yob + (size_t)n * NSTRIDE + (size_t)(p0 + wn * 64 + lo) * 768 + hi * 8;

    f32x4 acc[4][4];
#pragma unroll
    for (int mt = 0; mt < 4; mt++)
#pragma unroll
        for (int nt = 0; nt < 4; nt++) acc[mt][nt] = (f32x4){0.f, 0.f, 0.f, 0.f};

    for (int k0 = 0; k0 < 768; k0 += 32) {
        bf16x8 af[4], bf[4];
#pragma unroll
        for (int mt = 0; mt < 4; mt++)
            af[mt] = *(const bf16x8*)(Ap + (size_t)mt * 16 * 768 + k0);
#pragma unroll
        for (int nt = 0; nt < 4; nt++)
            bf[nt] = *(const bf16x8*)(Bp + (size_t)nt * 16 * 768 + k0);
#pragma unroll
        for (int mt = 0; mt < 4; mt++)
#pragma unroll
            for (int nt = 0; nt < 4; nt++)
                acc[mt][nt] = __builtin_amdgcn_mfma_f32_16x16x32_bf16(af[mt], bf[nt], acc[mt][nt], 0, 0, 0);
    }

    const float* xn = x + (size_t)n * NSTRIDE;
    float* on = out + (size_t)n * NSTRIDE;
#pragma unroll
    for (int mt = 0; mt < 4; mt++)
#pragma unroll
        for (int nt = 0; nt < 4; nt++)
#pragma unroll
            for (int r = 0; r < 4; r++) {
                int oo = m0 + wm * 64 + mt * 16 + hi * 4 + r;
                int p  = p0 + wn * 64 + nt * 16 + lo;
                size_t idx = (size_t)oo * 256 + p;
                on[idx] = (xn[idx] * 0.7f + acc[mt][nt][r] * 0.3f) * 1.3130643f;
            }
}

// ---------------------------------------------------------------------------
extern "C" void kernel_launch(void* const* d_in, const int* in_sizes, int n_in,
                              void* d_out, int out_size, void* d_ws, size_t ws_size,
                              hipStream_t stream) {
    const float* x     = (const float*)d_in[0];
    const float* wqkv  = (const float*)d_in[1];
    const float* wproj = (const float*)d_in[2];
    float* out = (float*)d_out;

    float*  Opart = (float*)d_ws;                             // 24*36*16384
    float*  lpart = Opart + (size_t)24 * 36 * 16384;          // 24*36*256
    bf16_t* wqkv_nb  = (bf16_t*)(lpart + (size_t)24 * 36 * 256);
    bf16_t* wproj_nb = wqkv_nb + (size_t)2304 * 768;
    bf16_t* xt       = wproj_nb + (size_t)768 * 768;
    bf16_t* qkvb     = xt + NSTRIDE * 16;
    bf16_t* yob      = qkvb + 3 * QKV_ONE;

    va_norm_w<<<3072, 256, 0, stream>>>(wqkv, wproj, wqkv_nb);
    va_x2bf<<<dim3(24, 8, 16), 256, 0, stream>>>(x, xt);
    va_qkv_mfma<<<dim3(2, 18, 16), 256, 0, stream>>>(wqkv_nb, xt, qkvb);
    va_attn<<<dim3(36, 24), 256, 0, stream>>>(qkvb, Opart, lpart);
    va_merge<<<3072, 256, 0, stream>>>(Opart, lpart, yob);
    va_proj_mfma<<<dim3(2, 6, 16), 256, 0, stream>>>(wproj_nb, yob, x, out);
}

// Round 12
// 268.192 us; speedup vs baseline: 1.6426x; 1.0270x over previous
//
#include <hip/hip_runtime.h>

typedef __bf16 bf16_t;
typedef __bf16 bf16x4 __attribute__((ext_vector_type(4)));
typedef __bf16 bf16x8 __attribute__((ext_vector_type(8)));
typedef float  f32x4  __attribute__((ext_vector_type(4)));

// Problem constants (setup_inputs: b=2, t=8, C=768, h=w=16)
static constexpr int NHEADS = 12, HC = 64, HW = 256, SEQ = 2048;
static constexpr size_t QKV_ONE = (size_t)2 * NHEADS * SEQ * HC;   // 3145728 elems per q/k/v slab
static constexpr size_t NSTRIDE = 768 * 256;                        // 196608

// ---------------------------------------------------------------------------
// mp_weight for BOTH weights in one launch. wproj columns permuted to
// j = head*64 + c so yo can live in natural [head][c] channel order.
// ---------------------------------------------------------------------------
__global__ __launch_bounds__(256) void va_norm_w(const float* __restrict__ wqkv,
                                                 const float* __restrict__ wproj,
                                                 bf16_t* __restrict__ out) {
    int row = blockIdx.x;
    bool is_proj = (row >= 2304);
    const float* wr = is_proj ? wproj + (size_t)(row - 2304) * 768
                              : wqkv + (size_t)row * 768;
    float part = 0.f;
    for (int i = threadIdx.x; i < 768; i += 256) { float v = wr[i]; part += v * v; }
#pragma unroll
    for (int off = 32; off > 0; off >>= 1) part += __shfl_down(part, off, 64);
    __shared__ float red[4];
    if ((threadIdx.x & 63) == 0) red[threadIdx.x >> 6] = part;
    __syncthreads();
    if (threadIdx.x == 0) {
        float s = red[0] + red[1] + red[2] + red[3];
        red[0] = 1.0f / (2.7712813e-3f + sqrtf(s));   // EPS*sqrt(768) + ||w||
    }
    __syncthreads();
    float sc = red[0];
    for (int i = threadIdx.x; i < 768; i += 256) {
        int j = is_proj ? ((i % 12) * 64 + i / 12) : i;   // column permute for wproj
        out[(size_t)row * 768 + j] = (bf16_t)(wr[i] * sc);
    }
}

// ---------------------------------------------------------------------------
// x fp32 [n][768 c][256 p]  ->  xt bf16 [n][256 p][768 c]
// ---------------------------------------------------------------------------
__global__ __launch_bounds__(256) void va_x2bf(const float* __restrict__ x,
                                               bf16_t* __restrict__ xt) {
    int n  = blockIdx.z;
    int c0 = blockIdx.x * 32;
    int p0 = blockIdx.y * 32;
    __shared__ float sm[32][33];
    int tx = threadIdx.x & 31, ty = threadIdx.x >> 5;
    const float* xp = x + (size_t)n * NSTRIDE;
#pragma unroll
    for (int i = 0; i < 4; i++)
        sm[ty + i * 8][tx] = xp[(size_t)(c0 + ty + i * 8) * 256 + p0 + tx];
    __syncthreads();
    bf16_t* xo = xt + (size_t)n * NSTRIDE;
#pragma unroll
    for (int i = 0; i < 4; i++)
        xo[(size_t)(p0 + ty + i * 8) * 768 + c0 + tx] = (bf16_t)sm[tx][ty + i * 8];
}

// ---------------------------------------------------------------------------
// QKV GEMM via MFMA, RoPE + q-scale fused in epilogue. (unchanged)
// ---------------------------------------------------------------------------
__global__ __launch_bounds__(256, 4) void va_qkv_mfma(const bf16_t* __restrict__ Wb,
                                                      const bf16_t* __restrict__ xt,
                                                      bf16_t* __restrict__ qkvb) {
    int n  = blockIdx.z;
    int m0 = blockIdx.y * 128;
    int p0 = blockIdx.x * 128;
    int tid = threadIdx.x;
    int lane = tid & 63, w = tid >> 6;
    int lo = lane & 15, hi = lane >> 4;
    int wm = w >> 1, wn = w & 1;

    const bf16_t* Ap = Wb + (size_t)(m0 + wm * 64 + lo) * 768 + hi * 8;
    const bf16_t* Bp = xt + (size_t)n * NSTRIDE + (size_t)(p0 + wn * 64 + lo) * 768 + hi * 8;

    f32x4 acc[4][4];
#pragma unroll
    for (int mt = 0; mt < 4; mt++)
#pragma unroll
        for (int nt = 0; nt < 4; nt++) acc[mt][nt] = (f32x4){0.f, 0.f, 0.f, 0.f};

    for (int k0 = 0; k0 < 768; k0 += 32) {
        bf16x8 af[4], bf[4];
#pragma unroll
        for (int mt = 0; mt < 4; mt++)
            af[mt] = *(const bf16x8*)(Ap + (size_t)mt * 16 * 768 + k0);
#pragma unroll
        for (int nt = 0; nt < 4; nt++)
            bf[nt] = *(const bf16x8*)(Bp + (size_t)nt * 16 * 768 + k0);
#pragma unroll
        for (int mt = 0; mt < 4; mt++)
#pragma unroll
            for (int nt = 0; nt < 4; nt++)
                acc[mt][nt] = __builtin_amdgcn_mfma_f32_16x16x32_bf16(af[mt], bf[nt], acc[mt][nt], 0, 0, 0);
    }

    int head_global = (m0 + wm * 64) >> 6;
    int qkv_idx = head_global / 12;
    int head    = head_global % 12;
    int b = n >> 3, tt = n & 7;
    int bm = b * 12 + head;
    if (qkv_idx < 2) {
        float qsc = (qkv_idx == 0) ? 0.125f : 1.0f;
        float ttf = (float)tt;
#pragma unroll
        for (int mt = 0; mt < 2; mt++)
#pragma unroll
            for (int r = 0; r < 4; r++) {
                int j = mt * 16 + hi * 4 + r;
                float ang = ttf * __expf(-(float)j * 0.2878231366242557f);
                float cs = __cosf(ang), sn = __sinf(ang);
#pragma unroll
                for (int nt = 0; nt < 4; nt++) {
                    float x1 = acc[mt][nt][r], x2 = acc[mt + 2][nt][r];
                    acc[mt][nt][r]     = (x1 * cs - x2 * sn) * qsc;
                    acc[mt + 2][nt][r] = (x1 * sn + x2 * cs) * qsc;
                }
            }
        bf16_t* dst = qkvb + (size_t)qkv_idx * QKV_ONE + ((size_t)bm * SEQ + (size_t)tt * HW) * HC;
#pragma unroll
        for (int mt = 0; mt < 4; mt++)
#pragma unroll
            for (int nt = 0; nt < 4; nt++)
#pragma unroll
                for (int r = 0; r < 4; r++) {
                    int cc = mt * 16 + hi * 4 + r;
                    int p  = p0 + wn * 64 + nt * 16 + lo;
                    dst[(size_t)p * HC + cc] = (bf16_t)acc[mt][nt][r];
                }
    } else {
        bf16_t* dst = qkvb + 2 * QKV_ONE + (size_t)bm * HC * SEQ + (size_t)tt * HW;
#pragma unroll
        for (int mt = 0; mt < 4; mt++)
#pragma unroll
            for (int nt = 0; nt < 4; nt++)
#pragma unroll
                for (int r = 0; r < 4; r++) {
                    int cc = mt * 16 + hi * 4 + r;
                    int p  = p0 + wn * 64 + nt * 16 + lo;
                    dst[(size_t)cc * SEQ + p] = (bf16_t)acc[mt][nt][r];
                }
    }
}

// ---------------------------------------------------------------------------
// MFMA flash attention v6: split-K with private partial slabs, now stored
// bf16 in natural [q][c] order via a wave-private LDS transpose (reusing PBw)
// so every global store instruction is a dense contiguous 1KB write — kills
// round 11's 3.4x write-RMW amplification AND halves partial bytes.
// ---------------------------------------------------------------------------
__global__ __launch_bounds__(256, 3) void va_attn(const bf16_t* __restrict__ qkvb,
                                                  bf16_t* __restrict__ Opart,
                                                  float* __restrict__ lpart) {
    int pidx = blockIdx.x;         // 0..35  -> (f, kf<=f)
    int bm   = blockIdx.y;         // 0..23
    int f = 0;
    while ((f + 1) * (f + 2) / 2 <= pidx) f++;
    int kf = pidx - f * (f + 1) / 2;

    int tid = threadIdx.x;
    int w = tid >> 6, lane = tid & 63;
    int lo = lane & 15, hi = lane >> 4;
    int lx = lo & 7;               // swizzle key

    const bf16_t* qbase = qkvb + (size_t)bm * SEQ * HC;
    const bf16_t* kbase = qkvb + QKV_ONE + (size_t)bm * SEQ * HC;
    const bf16_t* vbase = qkvb + 2 * QKV_ONE + (size_t)bm * HC * SEQ;
    const bf16_t* kfbase = kbase + (size_t)(kf * 256) * HC;
    const bf16_t* vfbase = vbase + kf * 256;

    __shared__ bf16_t KsF[64 * 64];
    __shared__ bf16_t VsF[64 * 64];
    __shared__ bf16_t PBF[4][64 * 64];
    bf16_t* PBw = PBF[w];

    int e0 = tid, e1 = tid + 256;
    int kr0 = e0 >> 3, cs0 = e0 & 7;
    int kr1 = e1 >> 3, cs1 = e1 & 7;
    int kc0 = (cs0 ^ (kr0 & 7)) * 8;
    int kc1 = (cs1 ^ (kr1 & 7)) * 8;

    bf16x8 sK0 = *(const bf16x8*)(kfbase + (size_t)kr0 * HC + kc0);
    bf16x8 sK1 = *(const bf16x8*)(kfbase + (size_t)kr1 * HC + kc1);
    bf16x8 sV0 = *(const bf16x8*)(vfbase + (size_t)kr0 * SEQ + kc0);
    bf16x8 sV1 = *(const bf16x8*)(vfbase + (size_t)kr1 * SEQ + kc1);

    const bf16_t* qrow = qbase + (size_t)(f * 256 + w * 64 + lo) * HC;
    bf16x8 qf[4][2];
#pragma unroll
    for (int nq = 0; nq < 4; nq++) {
        qf[nq][0] = *(const bf16x8*)(qrow + (size_t)nq * 16 * HC + hi * 8);
        qf[nq][1] = *(const bf16x8*)(qrow + (size_t)nq * 16 * HC + 32 + hi * 8);
    }
    f32x4 o[4][4];
#pragma unroll
    for (int ct = 0; ct < 4; ct++)
#pragma unroll
        for (int nq = 0; nq < 4; nq++) o[ct][nq] = (f32x4){0.f, 0.f, 0.f, 0.f};
    float l4[4] = {0.f, 0.f, 0.f, 0.f};

    for (int kt = 0; kt < 4; kt++) {
        __syncthreads();
        *(bf16x8*)(KsF + e0 * 8) = sK0;
        *(bf16x8*)(KsF + e1 * 8) = sK1;
        *(bf16x8*)(VsF + e0 * 8) = sV0;
        *(bf16x8*)(VsF + e1 * 8) = sV1;
        __syncthreads();
        if (kt < 3) {
            const bf16_t* kg = kfbase + (size_t)((kt + 1) * 64) * HC;
            const bf16_t* vg = vfbase + (kt + 1) * 64;
            sK0 = *(const bf16x8*)(kg + (size_t)kr0 * HC + kc0);
            sK1 = *(const bf16x8*)(kg + (size_t)kr1 * HC + kc1);
            sV0 = *(const bf16x8*)(vg + (size_t)kr0 * SEQ + kc0);
            sV1 = *(const bf16x8*)(vg + (size_t)kr1 * SEQ + kc1);
        }
#pragma unroll
        for (int mt = 0; mt < 4; mt++) {
            bf16x8 ka0 = *(const bf16x8*)(KsF + (mt * 16 + lo) * 64 + (hi ^ lx) * 8);
            bf16x8 ka1 = *(const bf16x8*)(KsF + (mt * 16 + lo) * 64 + ((4 + hi) ^ lx) * 8);
#pragma unroll
            for (int nq = 0; nq < 4; nq++) {
                f32x4 s = (f32x4){0.f, 0.f, 0.f, 0.f};
                s = __builtin_amdgcn_mfma_f32_16x16x32_bf16(ka0, qf[nq][0], s, 0, 0, 0);
                s = __builtin_amdgcn_mfma_f32_16x16x32_bf16(ka1, qf[nq][1], s, 0, 0, 0);
                bf16x4 pk;
#pragma unroll
                for (int r = 0; r < 4; r++) {
                    float p = __expf(s[r]);
                    l4[nq] += p;
                    pk[r] = (bf16_t)p;
                }
                *(bf16x4*)(PBw + (nq * 16 + lo) * 64 +
                           (((2 * mt + (hi >> 1)) ^ lx) * 8) + (hi & 1) * 4) = pk;
            }
        }
        bf16x8 pb0[4], pb1[4];
#pragma unroll
        for (int nq = 0; nq < 4; nq++) {
            pb0[nq] = *(const bf16x8*)(PBw + (nq * 16 + lo) * 64 + (hi ^ lx) * 8);
            pb1[nq] = *(const bf16x8*)(PBw + (nq * 16 + lo) * 64 + ((4 + hi) ^ lx) * 8);
        }
#pragma unroll
        for (int ct = 0; ct < 4; ct++) {
            bf16x8 va0 = *(const bf16x8*)(VsF + (ct * 16 + lo) * 64 + (hi ^ lx) * 8);
            bf16x8 va1 = *(const bf16x8*)(VsF + (ct * 16 + lo) * 64 + ((4 + hi) ^ lx) * 8);
#pragma unroll
            for (int nq = 0; nq < 4; nq++) {
                o[ct][nq] = __builtin_amdgcn_mfma_f32_16x16x32_bf16(va0, pb0[nq], o[ct][nq], 0, 0, 0);
                o[ct][nq] = __builtin_amdgcn_mfma_f32_16x16x32_bf16(va1, pb1[nq], o[ct][nq], 0, 0, 0);
            }
        }
    }
    // ---- l reduction (per query)
#pragma unroll
    for (int nq = 0; nq < 4; nq++) {
        l4[nq] += __shfl_xor(l4[nq], 16, 64);
        l4[nq] += __shfl_xor(l4[nq], 32, 64);
    }
    if (hi == 0) {
        float* lb = lpart + (size_t)(bm * 36 + pidx) * 256 + w * 64;
#pragma unroll
        for (int nq = 0; nq < 4; nq++) lb[nq * 16 + lo] = l4[nq];
    }
    // ---- O partial: wave-private LDS transpose (PBw reuse, no barrier
    // needed: DS pipe is in-order per wave) -> dense bf16 [q][c] stores.
    // Write: row = q_local = nq*16+lo, col c = ct*16+hi*4+r (P^T pattern).
#pragma unroll
    for (int ct = 0; ct < 4; ct++)
#pragma unroll
        for (int nq = 0; nq < 4; nq++) {
            bf16x4 ov;
#pragma unroll
            for (int r = 0; r < 4; r++) ov[r] = (bf16_t)o[ct][nq][r];
            *(bf16x4*)(PBw + (nq * 16 + lo) * 64 +
                       (((2 * ct + (hi >> 1)) ^ lx) * 8) + (hi & 1) * 4) = ov;
        }
    bf16_t* Ob = Opart + (size_t)(bm * 36 + pidx) * 16384 + (size_t)w * 4096;
#pragma unroll
    for (int i = 0; i < 8; i++) {
        int row = i * 8 + (lane >> 3);
        int j   = lane & 7;
        bf16x8 v = *(const bf16x8*)(PBw + row * 64 + ((j ^ (row & 7)) * 8));
        *(bf16x8*)(Ob + (size_t)row * 64 + j * 8) = v;   // dense 1KB/instr
    }
}

// ---------------------------------------------------------------------------
// merge v3: bf16 slabs, one bf16x8 chunk per thread, dense reads + writes.
// 393216 chunks = 1536 blocks x 256 threads.
// ---------------------------------------------------------------------------
__global__ __launch_bounds__(256) void va_merge(const bf16_t* __restrict__ Opart,
                                                const float* __restrict__ lpart,
                                                bf16_t* __restrict__ yob) {
    int t = blockIdx.x * 256 + threadIdx.x;   // bf16x8 chunk id, < 393216
    int bm   = t >> 14;                       // 0..23  (16384 chunks per bm)
    int rem  = t & 16383;
    int f    = rem >> 11;                     // 0..7   (2048 chunks per f)
    int rem2 = rem & 2047;
    int q    = rem2 >> 3;                     // 0..255
    int c8   = rem2 & 7;                      // 16-byte chunk within 64 c
    int sbase = bm * 36 + f * (f + 1) / 2;

    float lsum = 0.f;
    for (int kf = 0; kf <= f; kf++)
        lsum += lpart[(size_t)(sbase + kf) * 256 + q];

    float v[8] = {0.f, 0.f, 0.f, 0.f, 0.f, 0.f, 0.f, 0.f};
    const bf16_t* Ob = Opart + (size_t)sbase * 16384 + (size_t)q * 64 + c8 * 8;
    for (int kf = 0; kf <= f; kf++) {
        bf16x8 pv = *(const bf16x8*)(Ob + (size_t)kf * 16384);
#pragma unroll
        for (int r = 0; r < 8; r++) v[r] += (float)pv[r];
    }

    float invl = 1.0f / lsum;
    int head = bm % 12, b = bm / 12;
    bf16x8 o8;
#pragma unroll
    for (int r = 0; r < 8; r++) o8[r] = (bf16_t)(v[r] * invl);
    *(bf16x8*)(yob + (size_t)(b * 8 + f) * NSTRIDE + (size_t)q * 768 + head * 64 + c8 * 8) = o8;
}

// ---------------------------------------------------------------------------
// Proj GEMM via MFMA + mp_sum. (unchanged; weights column-permuted upstream)
// ---------------------------------------------------------------------------
__global__ __launch_bounds__(256, 4) void va_proj_mfma(const bf16_t* __restrict__ Wb,
                                                       const bf16_t* __restrict__ yob,
                                                       const float* __restrict__ x,
                                                       float* __restrict__ out) {
    int n  = blockIdx.z;
    int m0 = blockIdx.y * 128;
    int p0 = blockIdx.x * 128;
    int tid = threadIdx.x;
    int lane = tid & 63, w = tid >> 6;
    int lo = lane & 15, hi = lane >> 4;
    int wm = w >> 1, wn = w & 1;

    const bf16_t* Ap = Wb + (size_t)(m0 + wm * 64 + lo) * 768 + hi * 8;
    const bf16_t* Bp = yob + (size_t)n * NSTRIDE + (size_t)(p0 + wn * 64 + lo) * 768 + hi * 8;

    f32x4 acc[4][4];
#pragma unroll
    for (int mt = 0; mt < 4; mt++)
#pragma unroll
        for (int nt = 0; nt < 4; nt++) acc[mt][nt] = (f32x4){0.f, 0.f, 0.f, 0.f};

    for (int k0 = 0; k0 < 768; k0 += 32) {
        bf16x8 af[4], bf[4];
#pragma unroll
        for (int mt = 0; mt < 4; mt++)
            af[mt] = *(const bf16x8*)(Ap + (size_t)mt * 16 * 768 + k0);
#pragma unroll
        for (int nt = 0; nt < 4; nt++)
            bf[nt] = *(const bf16x8*)(Bp + (size_t)nt * 16 * 768 + k0);
#pragma unroll
        for (int mt = 0; mt < 4; mt++)
#pragma unroll
            for (int nt = 0; nt < 4; nt++)
                acc[mt][nt] = __builtin_amdgcn_mfma_f32_16x16x32_bf16(af[mt], bf[nt], acc[mt][nt], 0, 0, 0);
    }

    const float* xn = x + (size_t)n * NSTRIDE;
    float* on = out + (size_t)n * NSTRIDE;
#pragma unroll
    for (int mt = 0; mt < 4; mt++)
#pragma unroll
        for (int nt = 0; nt < 4; nt++)
#pragma unroll
            for (int r = 0; r < 4; r++) {
                int oo = m0 + wm * 64 + mt * 16 + hi * 4 + r;
                int p  = p0 + wn * 64 + nt * 16 + lo;
                size_t idx = (size_t)oo * 256 + p;
                on[idx] = (xn[idx] * 0.7f + acc[mt][nt][r] * 0.3f) * 1.3130643f;
            }
}

// ---------------------------------------------------------------------------
extern "C" void kernel_launch(void* const* d_in, const int* in_sizes, int n_in,
                              void* d_out, int out_size, void* d_ws, size_t ws_size,
                              hipStream_t stream) {
    const float* x     = (const float*)d_in[0];
    const float* wqkv  = (const float*)d_in[1];
    const float* wproj = (const float*)d_in[2];
    float* out = (float*)d_out;

    bf16_t* Opart = (bf16_t*)d_ws;                            // 24*36*16384 bf16 = 28.3 MB
    float*  lpart = (float*)(Opart + (size_t)24 * 36 * 16384); // 24*36*256 fp32
    bf16_t* wqkv_nb  = (bf16_t*)(lpart + (size_t)24 * 36 * 256);
    bf16_t* wproj_nb = wqkv_nb + (size_t)2304 * 768;
    bf16_t* xt       = wproj_nb + (size_t)768 * 768;
    bf16_t* qkvb     = xt + NSTRIDE * 16;
    bf16_t* yob      = qkvb + 3 * QKV_ONE;

    va_norm_w<<<3072, 256, 0, stream>>>(wqkv, wproj, wqkv_nb);
    va_x2bf<<<dim3(24, 8, 16), 256, 0, stream>>>(x, xt);
    va_qkv_mfma<<<dim3(2, 18, 16), 256, 0, stream>>>(wqkv_nb, xt, qkvb);
    va_attn<<<dim3(36, 24), 256, 0, stream>>>(qkvb, Opart, lpart);
    va_merge<<<1536, 256, 0, stream>>>(Opart, lpart, yob);
    va_proj_mfma<<<dim3(2, 6, 16), 256, 0, stream>>>(wproj_nb, yob, x, out);
}

// Round 13
// 259.700 us; speedup vs baseline: 1.6963x; 1.0327x over previous
//
#include <hip/hip_runtime.h>

typedef __bf16 bf16_t;
typedef __bf16 bf16x4 __attribute__((ext_vector_type(4)));
typedef __bf16 bf16x8 __attribute__((ext_vector_type(8)));
typedef float  f32x4  __attribute__((ext_vector_type(4)));

// Problem constants (setup_inputs: b=2, t=8, C=768, h=w=16)
static constexpr int NHEADS = 12, HC = 64, HW = 256, SEQ = 2048;
static constexpr size_t QKV_ONE = (size_t)2 * NHEADS * SEQ * HC;   // 3145728 elems per q/k/v slab
static constexpr size_t NSTRIDE = 768 * 256;                        // 196608

// ---------------------------------------------------------------------------
// prep: blocks 0..3071 = mp_weight rows (wqkv then wproj, proj columns
// permuted to j=head*64+c); blocks 3072..6143 = x fp32->bf16 transpose tiles.
// ---------------------------------------------------------------------------
__global__ __launch_bounds__(256) void va_prep(const float* __restrict__ wqkv,
                                               const float* __restrict__ wproj,
                                               const float* __restrict__ x,
                                               bf16_t* __restrict__ wout,
                                               bf16_t* __restrict__ xt) {
    int blk = blockIdx.x;
    if (blk < 3072) {
        int row = blk;
        bool is_proj = (row >= 2304);
        const float* wr = is_proj ? wproj + (size_t)(row - 2304) * 768
                                  : wqkv + (size_t)row * 768;
        float part = 0.f;
        for (int i = threadIdx.x; i < 768; i += 256) { float v = wr[i]; part += v * v; }
#pragma unroll
        for (int off = 32; off > 0; off >>= 1) part += __shfl_down(part, off, 64);
        __shared__ float red[4];
        if ((threadIdx.x & 63) == 0) red[threadIdx.x >> 6] = part;
        __syncthreads();
        if (threadIdx.x == 0) {
            float s = red[0] + red[1] + red[2] + red[3];
            red[0] = 1.0f / (2.7712813e-3f + sqrtf(s));   // EPS*sqrt(768) + ||w||
        }
        __syncthreads();
        float sc = red[0];
        for (int i = threadIdx.x; i < 768; i += 256) {
            int j = is_proj ? ((i % 12) * 64 + i / 12) : i;
            wout[(size_t)row * 768 + j] = (bf16_t)(wr[i] * sc);
        }
    } else {
        int t = blk - 3072;                 // [0, 3072)
        int n  = t & 15;
        int rest = t >> 4;                  // [0,192)
        int p0 = (rest & 7) * 32;
        int c0 = (rest >> 3) * 32;          // [0,24) * 32
        __shared__ float sm[32][33];
        int tx = threadIdx.x & 31, ty = threadIdx.x >> 5;
        const float* xp = x + (size_t)n * NSTRIDE;
#pragma unroll
        for (int i = 0; i < 4; i++)
            sm[ty + i * 8][tx] = xp[(size_t)(c0 + ty + i * 8) * 256 + p0 + tx];
        __syncthreads();
        bf16_t* xo = xt + (size_t)n * NSTRIDE;
#pragma unroll
        for (int i = 0; i < 4; i++)
            xo[(size_t)(p0 + ty + i * 8) * 768 + c0 + tx] = (bf16_t)sm[tx][ty + i * 8];
    }
}

// ---------------------------------------------------------------------------
// QKV GEMM via MFMA, RoPE + q-scale fused. 1D grid (576) with XCD-aware
// remap: idx%8 + bit -> n, so all blocks of one n land on one XCD and share
// its xt panel / W rows through that XCD's L2.
// ---------------------------------------------------------------------------
__global__ __launch_bounds__(256, 4) void va_qkv_mfma(const bf16_t* __restrict__ Wb,
                                                      const bf16_t* __restrict__ xt,
                                                      bf16_t* __restrict__ qkvb) {
    int idx = blockIdx.x;                   // [0,576)
    int n  = (idx & 7) + 8 * ((idx >> 3) & 1);
    int rest = idx >> 4;                    // [0,36)
    int p0 = (rest & 1) * 128;
    int m0 = (rest >> 1) * 128;             // [0,18)*128
    int tid = threadIdx.x;
    int lane = tid & 63, w = tid >> 6;
    int lo = lane & 15, hi = lane >> 4;
    int wm = w >> 1, wn = w & 1;

    const bf16_t* Ap = Wb + (size_t)(m0 + wm * 64 + lo) * 768 + hi * 8;
    const bf16_t* Bp = xt + (size_t)n * NSTRIDE + (size_t)(p0 + wn * 64 + lo) * 768 + hi * 8;

    f32x4 acc[4][4];
#pragma unroll
    for (int mt = 0; mt < 4; mt++)
#pragma unroll
        for (int nt = 0; nt < 4; nt++) acc[mt][nt] = (f32x4){0.f, 0.f, 0.f, 0.f};

    for (int k0 = 0; k0 < 768; k0 += 32) {
        bf16x8 af[4], bf[4];
#pragma unroll
        for (int mt = 0; mt < 4; mt++)
            af[mt] = *(const bf16x8*)(Ap + (size_t)mt * 16 * 768 + k0);
#pragma unroll
        for (int nt = 0; nt < 4; nt++)
            bf[nt] = *(const bf16x8*)(Bp + (size_t)nt * 16 * 768 + k0);
#pragma unroll
        for (int mt = 0; mt < 4; mt++)
#pragma unroll
            for (int nt = 0; nt < 4; nt++)
                acc[mt][nt] = __builtin_amdgcn_mfma_f32_16x16x32_bf16(af[mt], bf[nt], acc[mt][nt], 0, 0, 0);
    }

    int head_global = (m0 + wm * 64) >> 6;
    int qkv_idx = head_global / 12;
    int head    = head_global % 12;
    int b = n >> 3, tt = n & 7;
    int bm = b * 12 + head;
    if (qkv_idx < 2) {
        float qsc = (qkv_idx == 0) ? 0.125f : 1.0f;
        float ttf = (float)tt;
#pragma unroll
        for (int mt = 0; mt < 2; mt++)
#pragma unroll
            for (int r = 0; r < 4; r++) {
                int j = mt * 16 + hi * 4 + r;
                float ang = ttf * __expf(-(float)j * 0.2878231366242557f);
                float cs = __cosf(ang), sn = __sinf(ang);
#pragma unroll
                for (int nt = 0; nt < 4; nt++) {
                    float x1 = acc[mt][nt][r], x2 = acc[mt + 2][nt][r];
                    acc[mt][nt][r]     = (x1 * cs - x2 * sn) * qsc;
                    acc[mt + 2][nt][r] = (x1 * sn + x2 * cs) * qsc;
                }
            }
        bf16_t* dst = qkvb + (size_t)qkv_idx * QKV_ONE + ((size_t)bm * SEQ + (size_t)tt * HW) * HC;
#pragma unroll
        for (int mt = 0; mt < 4; mt++)
#pragma unroll
            for (int nt = 0; nt < 4; nt++)
#pragma unroll
                for (int r = 0; r < 4; r++) {
                    int cc = mt * 16 + hi * 4 + r;
                    int p  = p0 + wn * 64 + nt * 16 + lo;
                    dst[(size_t)p * HC + cc] = (bf16_t)acc[mt][nt][r];
                }
    } else {
        bf16_t* dst = qkvb + 2 * QKV_ONE + (size_t)bm * HC * SEQ + (size_t)tt * HW;
#pragma unroll
        for (int mt = 0; mt < 4; mt++)
#pragma unroll
            for (int nt = 0; nt < 4; nt++)
#pragma unroll
                for (int r = 0; r < 4; r++) {
                    int cc = mt * 16 + hi * 4 + r;
                    int p  = p0 + wn * 64 + nt * 16 + lo;
                    dst[(size_t)cc * SEQ + p] = (bf16_t)acc[mt][nt][r];
                }
    }
}

// ---------------------------------------------------------------------------
// MFMA flash attention v7: split-K, bf16 private slabs, XCD-aware remap:
// all 36 blocks of one bm share an XCD -> q/k/v slices fill L2 once
// (2.3 MB per XCD for its 3 bm's) instead of up to 8 redundant L3 fills.
// ---------------------------------------------------------------------------
__global__ __launch_bounds__(256, 3) void va_attn(const bf16_t* __restrict__ qkvb,
                                                  bf16_t* __restrict__ Opart,
                                                  float* __restrict__ lpart) {
    int idx = blockIdx.x;                   // [0,864)
    int g = idx >> 3;                       // [0,108)
    int bm = (idx & 7) + 8 * (g / 36);      // same-bm -> same idx%8 -> same XCD
    int pidx = g % 36;                      // (f, kf<=f)
    int f = 0;
    while ((f + 1) * (f + 2) / 2 <= pidx) f++;
    int kf = pidx - f * (f + 1) / 2;

    int tid = threadIdx.x;
    int w = tid >> 6, lane = tid & 63;
    int lo = lane & 15, hi = lane >> 4;
    int lx = lo & 7;               // swizzle key

    const bf16_t* qbase = qkvb + (size_t)bm * SEQ * HC;
    const bf16_t* kbase = qkvb + QKV_ONE + (size_t)bm * SEQ * HC;
    const bf16_t* vbase = qkvb + 2 * QKV_ONE + (size_t)bm * HC * SEQ;
    const bf16_t* kfbase = kbase + (size_t)(kf * 256) * HC;
    const bf16_t* vfbase = vbase + kf * 256;

    __shared__ bf16_t KsF[64 * 64];
    __shared__ bf16_t VsF[64 * 64];
    __shared__ bf16_t PBF[4][64 * 64];
    bf16_t* PBw = PBF[w];

    int e0 = tid, e1 = tid + 256;
    int kr0 = e0 >> 3, cs0 = e0 & 7;
    int kr1 = e1 >> 3, cs1 = e1 & 7;
    int kc0 = (cs0 ^ (kr0 & 7)) * 8;
    int kc1 = (cs1 ^ (kr1 & 7)) * 8;

    bf16x8 sK0 = *(const bf16x8*)(kfbase + (size_t)kr0 * HC + kc0);
    bf16x8 sK1 = *(const bf16x8*)(kfbase + (size_t)kr1 * HC + kc1);
    bf16x8 sV0 = *(const bf16x8*)(vfbase + (size_t)kr0 * SEQ + kc0);
    bf16x8 sV1 = *(const bf16x8*)(vfbase + (size_t)kr1 * SEQ + kc1);

    const bf16_t* qrow = qbase + (size_t)(f * 256 + w * 64 + lo) * HC;
    bf16x8 qf[4][2];
#pragma unroll
    for (int nq = 0; nq < 4; nq++) {
        qf[nq][0] = *(const bf16x8*)(qrow + (size_t)nq * 16 * HC + hi * 8);
        qf[nq][1] = *(const bf16x8*)(qrow + (size_t)nq * 16 * HC + 32 + hi * 8);
    }
    f32x4 o[4][4];
#pragma unroll
    for (int ct = 0; ct < 4; ct++)
#pragma unroll
        for (int nq = 0; nq < 4; nq++) o[ct][nq] = (f32x4){0.f, 0.f, 0.f, 0.f};
    float l4[4] = {0.f, 0.f, 0.f, 0.f};

    for (int kt = 0; kt < 4; kt++) {
        __syncthreads();
        *(bf16x8*)(KsF + e0 * 8) = sK0;
        *(bf16x8*)(KsF + e1 * 8) = sK1;
        *(bf16x8*)(VsF + e0 * 8) = sV0;
        *(bf16x8*)(VsF + e1 * 8) = sV1;
        __syncthreads();
        if (kt < 3) {
            const bf16_t* kg = kfbase + (size_t)((kt + 1) * 64) * HC;
            const bf16_t* vg = vfbase + (kt + 1) * 64;
            sK0 = *(const bf16x8*)(kg + (size_t)kr0 * HC + kc0);
            sK1 = *(const bf16x8*)(kg + (size_t)kr1 * HC + kc1);
            sV0 = *(const bf16x8*)(vg + (size_t)kr0 * SEQ + kc0);
            sV1 = *(const bf16x8*)(vg + (size_t)kr1 * SEQ + kc1);
        }
#pragma unroll
        for (int mt = 0; mt < 4; mt++) {
            bf16x8 ka0 = *(const bf16x8*)(KsF + (mt * 16 + lo) * 64 + (hi ^ lx) * 8);
            bf16x8 ka1 = *(const bf16x8*)(KsF + (mt * 16 + lo) * 64 + ((4 + hi) ^ lx) * 8);
#pragma unroll
            for (int nq = 0; nq < 4; nq++) {
                f32x4 s = (f32x4){0.f, 0.f, 0.f, 0.f};
                s = __builtin_amdgcn_mfma_f32_16x16x32_bf16(ka0, qf[nq][0], s, 0, 0, 0);
                s = __builtin_amdgcn_mfma_f32_16x16x32_bf16(ka1, qf[nq][1], s, 0, 0, 0);
                bf16x4 pk;
#pragma unroll
                for (int r = 0; r < 4; r++) {
                    float p = __expf(s[r]);
                    l4[nq] += p;
                    pk[r] = (bf16_t)p;
                }
                *(bf16x4*)(PBw + (nq * 16 + lo) * 64 +
                           (((2 * mt + (hi >> 1)) ^ lx) * 8) + (hi & 1) * 4) = pk;
            }
        }
        bf16x8 pb0[4], pb1[4];
#pragma unroll
        for (int nq = 0; nq < 4; nq++) {
            pb0[nq] = *(const bf16x8*)(PBw + (nq * 16 + lo) * 64 + (hi ^ lx) * 8);
            pb1[nq] = *(const bf16x8*)(PBw + (nq * 16 + lo) * 64 + ((4 + hi) ^ lx) * 8);
        }
#pragma unroll
        for (int ct = 0; ct < 4; ct++) {
            bf16x8 va0 = *(const bf16x8*)(VsF + (ct * 16 + lo) * 64 + (hi ^ lx) * 8);
            bf16x8 va1 = *(const bf16x8*)(VsF + (ct * 16 + lo) * 64 + ((4 + hi) ^ lx) * 8);
#pragma unroll
            for (int nq = 0; nq < 4; nq++) {
                o[ct][nq] = __builtin_amdgcn_mfma_f32_16x16x32_bf16(va0, pb0[nq], o[ct][nq], 0, 0, 0);
                o[ct][nq] = __builtin_amdgcn_mfma_f32_16x16x32_bf16(va1, pb1[nq], o[ct][nq], 0, 0, 0);
            }
        }
    }
#pragma unroll
    for (int nq = 0; nq < 4; nq++) {
        l4[nq] += __shfl_xor(l4[nq], 16, 64);
        l4[nq] += __shfl_xor(l4[nq], 32, 64);
    }
    if (hi == 0) {
        float* lb = lpart + (size_t)(bm * 36 + pidx) * 256 + w * 64;
#pragma unroll
        for (int nq = 0; nq < 4; nq++) lb[nq * 16 + lo] = l4[nq];
    }
    // O partial: wave-private LDS transpose -> dense bf16 [q][c] stores
#pragma unroll
    for (int ct = 0; ct < 4; ct++)
#pragma unroll
        for (int nq = 0; nq < 4; nq++) {
            bf16x4 ov;
#pragma unroll
            for (int r = 0; r < 4; r++) ov[r] = (bf16_t)o[ct][nq][r];
            *(bf16x4*)(PBw + (nq * 16 + lo) * 64 +
                       (((2 * ct + (hi >> 1)) ^ lx) * 8) + (hi & 1) * 4) = ov;
        }
    bf16_t* Ob = Opart + (size_t)(bm * 36 + pidx) * 16384 + (size_t)w * 4096;
#pragma unroll
    for (int i = 0; i < 8; i++) {
        int row = i * 8 + (lane >> 3);
        int j   = lane & 7;
        bf16x8 v = *(const bf16x8*)(PBw + row * 64 + ((j ^ (row & 7)) * 8));
        *(bf16x8*)(Ob + (size_t)row * 64 + j * 8) = v;
    }
}

// ---------------------------------------------------------------------------
// merge v4: XCD-remapped so each block reads slabs of a bm resident on its
// own XCD. One bf16x8 chunk per thread, dense.
// ---------------------------------------------------------------------------
__global__ __launch_bounds__(256) void va_merge(const bf16_t* __restrict__ Opart,
                                                const float* __restrict__ lpart,
                                                bf16_t* __restrict__ yob) {
    int idx = blockIdx.x;                   // [0,1536)
    int g = idx >> 3;                       // [0,192)
    int bm = (idx & 7) + 8 * (g >> 6);      // same-bm -> same XCD as attn
    int inner = g & 63;
    int rem = inner * 256 + threadIdx.x;    // [0,16384) chunk within bm
    int f    = rem >> 11;
    int rem2 = rem & 2047;
    int q    = rem2 >> 3;
    int c8   = rem2 & 7;
    int sbase = bm * 36 + f * (f + 1) / 2;

    float lsum = 0.f;
    for (int kf = 0; kf <= f; kf++)
        lsum += lpart[(size_t)(sbase + kf) * 256 + q];

    float v[8] = {0.f, 0.f, 0.f, 0.f, 0.f, 0.f, 0.f, 0.f};
    const bf16_t* Ob = Opart + (size_t)sbase * 16384 + (size_t)q * 64 + c8 * 8;
    for (int kf = 0; kf <= f; kf++) {
        bf16x8 pv = *(const bf16x8*)(Ob + (size_t)kf * 16384);
#pragma unroll
        for (int r = 0; r < 8; r++) v[r] += (float)pv[r];
    }

    float invl = 1.0f / lsum;
    int head = bm % 12, b = bm / 12;
    bf16x8 o8;
#pragma unroll
    for (int r = 0; r < 8; r++) o8[r] = (bf16_t)(v[r] * invl);
    *(bf16x8*)(yob + (size_t)(b * 8 + f) * NSTRIDE + (size_t)q * 768 + head * 64 + c8 * 8) = o8;
}

// ---------------------------------------------------------------------------
// Proj GEMM via MFMA + mp_sum. 1D grid (192), XCD-remapped by n.
// ---------------------------------------------------------------------------
__global__ __launch_bounds__(256, 4) void va_proj_mfma(const bf16_t* __restrict__ Wb,
                                                       const bf16_t* __restrict__ yob,
                                                       const float* __restrict__ x,
                                                       float* __restrict__ out) {
    int idx = blockIdx.x;                   // [0,192)
    int n  = (idx & 7) + 8 * ((idx >> 3) & 1);
    int rest = idx >> 4;                    // [0,12)
    int p0 = (rest & 1) * 128;
    int m0 = (rest >> 1) * 128;             // [0,6)*128
    int tid = threadIdx.x;
    int lane = tid & 63, w = tid >> 6;
    int lo = lane & 15, hi = lane >> 4;
    int wm = w >> 1, wn = w & 1;

    const bf16_t* Ap = Wb + (size_t)(m0 + wm * 64 + lo) * 768 + hi * 8;
    const bf16_t* Bp = yob + (size_t)n * NSTRIDE + (size_t)(p0 + wn * 64 + lo) * 768 + hi * 8;

    f32x4 acc[4][4];
#pragma unroll
    for (int mt = 0; mt < 4; mt++)
#pragma unroll
        for (int nt = 0; nt < 4; nt++) acc[mt][nt] = (f32x4){0.f, 0.f, 0.f, 0.f};

    for (int k0 = 0; k0 < 768; k0 += 32) {
        bf16x8 af[4], bf[4];
#pragma unroll
        for (int mt = 0; mt < 4; mt++)
            af[mt] = *(const bf16x8*)(Ap + (size_t)mt * 16 * 768 + k0);
#pragma unroll
        for (int nt = 0; nt < 4; nt++)
            bf[nt] = *(const bf16x8*)(Bp + (size_t)nt * 16 * 768 + k0);
#pragma unroll
        for (int mt = 0; mt < 4; mt++)
#pragma unroll
            for (int nt = 0; nt < 4; nt++)
                acc[mt][nt] = __builtin_amdgcn_mfma_f32_16x16x32_bf16(af[mt], bf[nt], acc[mt][nt], 0, 0, 0);
    }

    const float* xn = x + (size_t)n * NSTRIDE;
    float* on = out + (size_t)n * NSTRIDE;
#pragma unroll
    for (int mt = 0; mt < 4; mt++)
#pragma unroll
        for (int nt = 0; nt < 4; nt++)
#pragma unroll
            for (int r = 0; r < 4; r++) {
                int oo = m0 + wm * 64 + mt * 16 + hi * 4 + r;
                int p  = p0 + wn * 64 + nt * 16 + lo;
                size_t idx2 = (size_t)oo * 256 + p;
                on[idx2] = (xn[idx2] * 0.7f + acc[mt][nt][r] * 0.3f) * 1.3130643f;
            }
}

// ---------------------------------------------------------------------------
extern "C" void kernel_launch(void* const* d_in, const int* in_sizes, int n_in,
                              void* d_out, int out_size, void* d_ws, size_t ws_size,
                              hipStream_t stream) {
    const float* x     = (const float*)d_in[0];
    const float* wqkv  = (const float*)d_in[1];
    const float* wproj = (const float*)d_in[2];
    float* out = (float*)d_out;

    bf16_t* Opart = (bf16_t*)d_ws;                             // 24*36*16384 bf16
    float*  lpart = (float*)(Opart + (size_t)24 * 36 * 16384); // 24*36*256 fp32
    bf16_t* wqkv_nb  = (bf16_t*)(lpart + (size_t)24 * 36 * 256);
    bf16_t* wproj_nb = wqkv_nb + (size_t)2304 * 768;  (void)wproj_nb;
    bf16_t* xt       = wqkv_nb + (size_t)3072 * 768;
    bf16_t* qkvb     = xt + NSTRIDE * 16;
    bf16_t* yob      = qkvb + 3 * QKV_ONE;

    va_prep<<<6144, 256, 0, stream>>>(wqkv, wproj, x, wqkv_nb, xt);
    va_qkv_mfma<<<576, 256, 0, stream>>>(wqkv_nb, xt, qkvb);
    va_attn<<<864, 256, 0, stream>>>(qkvb, Opart, lpart);
    va_merge<<<1536, 256, 0, stream>>>(Opart, lpart, yob);
    va_proj_mfma<<<192, 256, 0, stream>>>(wqkv_nb + (size_t)2304 * 768, yob, x, out);
}

// Round 14
// 253.208 us; speedup vs baseline: 1.7398x; 1.0256x over previous
//
#include <hip/hip_runtime.h>

typedef __bf16 bf16_t;
typedef __bf16 bf16x4 __attribute__((ext_vector_type(4)));
typedef __bf16 bf16x8 __attribute__((ext_vector_type(8)));
typedef float  f32x4  __attribute__((ext_vector_type(4)));

// Problem constants (setup_inputs: b=2, t=8, C=768, h=w=16)
static constexpr int NHEADS = 12, HC = 64, HW = 256, SEQ = 2048;
static constexpr size_t QKV_ONE = (size_t)2 * NHEADS * SEQ * HC;   // 3145728 elems per q/k/v slab
static constexpr size_t NSTRIDE = 768 * 256;                        // 196608

// ---------------------------------------------------------------------------
// prep: blocks 0..3071 = mp_weight rows (wqkv then wproj, proj columns
// permuted to j=head*64+c); blocks 3072..6143 = x fp32->bf16 transpose tiles.
// ---------------------------------------------------------------------------
__global__ __launch_bounds__(256) void va_prep(const float* __restrict__ wqkv,
                                               const float* __restrict__ wproj,
                                               const float* __restrict__ x,
                                               bf16_t* __restrict__ wout,
                                               bf16_t* __restrict__ xt) {
    int blk = blockIdx.x;
    if (blk < 3072) {
        int row = blk;
        bool is_proj = (row >= 2304);
        const float* wr = is_proj ? wproj + (size_t)(row - 2304) * 768
                                  : wqkv + (size_t)row * 768;
        float part = 0.f;
        for (int i = threadIdx.x; i < 768; i += 256) { float v = wr[i]; part += v * v; }
#pragma unroll
        for (int off = 32; off > 0; off >>= 1) part += __shfl_down(part, off, 64);
        __shared__ float red[4];
        if ((threadIdx.x & 63) == 0) red[threadIdx.x >> 6] = part;
        __syncthreads();
        if (threadIdx.x == 0) {
            float s = red[0] + red[1] + red[2] + red[3];
            red[0] = 1.0f / (2.7712813e-3f + sqrtf(s));   // EPS*sqrt(768) + ||w||
        }
        __syncthreads();
        float sc = red[0];
        for (int i = threadIdx.x; i < 768; i += 256) {
            int j = is_proj ? ((i % 12) * 64 + i / 12) : i;
            wout[(size_t)row * 768 + j] = (bf16_t)(wr[i] * sc);
        }
    } else {
        int t = blk - 3072;                 // [0, 3072)
        int n  = t & 15;
        int rest = t >> 4;                  // [0,192)
        int p0 = (rest & 7) * 32;
        int c0 = (rest >> 3) * 32;          // [0,24) * 32
        __shared__ float sm[32][33];
        int tx = threadIdx.x & 31, ty = threadIdx.x >> 5;
        const float* xp = x + (size_t)n * NSTRIDE;
#pragma unroll
        for (int i = 0; i < 4; i++)
            sm[ty + i * 8][tx] = xp[(size_t)(c0 + ty + i * 8) * 256 + p0 + tx];
        __syncthreads();
        bf16_t* xo = xt + (size_t)n * NSTRIDE;
#pragma unroll
        for (int i = 0; i < 4; i++)
            xo[(size_t)(p0 + ty + i * 8) * 768 + c0 + tx] = (bf16_t)sm[tx][ty + i * 8];
    }
}

// ---------------------------------------------------------------------------
// QKV GEMM via MFMA, RoPE + q-scale fused. XCD-remapped by n. (unchanged)
// ---------------------------------------------------------------------------
__global__ __launch_bounds__(256, 4) void va_qkv_mfma(const bf16_t* __restrict__ Wb,
                                                      const bf16_t* __restrict__ xt,
                                                      bf16_t* __restrict__ qkvb) {
    int idx = blockIdx.x;                   // [0,576)
    int n  = (idx & 7) + 8 * ((idx >> 3) & 1);
    int rest = idx >> 4;                    // [0,36)
    int p0 = (rest & 1) * 128;
    int m0 = (rest >> 1) * 128;             // [0,18)*128
    int tid = threadIdx.x;
    int lane = tid & 63, w = tid >> 6;
    int lo = lane & 15, hi = lane >> 4;
    int wm = w >> 1, wn = w & 1;

    const bf16_t* Ap = Wb + (size_t)(m0 + wm * 64 + lo) * 768 + hi * 8;
    const bf16_t* Bp = xt + (size_t)n * NSTRIDE + (size_t)(p0 + wn * 64 + lo) * 768 + hi * 8;

    f32x4 acc[4][4];
#pragma unroll
    for (int mt = 0; mt < 4; mt++)
#pragma unroll
        for (int nt = 0; nt < 4; nt++) acc[mt][nt] = (f32x4){0.f, 0.f, 0.f, 0.f};

    for (int k0 = 0; k0 < 768; k0 += 32) {
        bf16x8 af[4], bf[4];
#pragma unroll
        for (int mt = 0; mt < 4; mt++)
            af[mt] = *(const bf16x8*)(Ap + (size_t)mt * 16 * 768 + k0);
#pragma unroll
        for (int nt = 0; nt < 4; nt++)
            bf[nt] = *(const bf16x8*)(Bp + (size_t)nt * 16 * 768 + k0);
#pragma unroll
        for (int mt = 0; mt < 4; mt++)
#pragma unroll
            for (int nt = 0; nt < 4; nt++)
                acc[mt][nt] = __builtin_amdgcn_mfma_f32_16x16x32_bf16(af[mt], bf[nt], acc[mt][nt], 0, 0, 0);
    }

    int head_global = (m0 + wm * 64) >> 6;
    int qkv_idx = head_global / 12;
    int head    = head_global % 12;
    int b = n >> 3, tt = n & 7;
    int bm = b * 12 + head;
    if (qkv_idx < 2) {
        float qsc = (qkv_idx == 0) ? 0.125f : 1.0f;
        float ttf = (float)tt;
#pragma unroll
        for (int mt = 0; mt < 2; mt++)
#pragma unroll
            for (int r = 0; r < 4; r++) {
                int j = mt * 16 + hi * 4 + r;
                float ang = ttf * __expf(-(float)j * 0.2878231366242557f);
                float cs = __cosf(ang), sn = __sinf(ang);
#pragma unroll
                for (int nt = 0; nt < 4; nt++) {
                    float x1 = acc[mt][nt][r], x2 = acc[mt + 2][nt][r];
                    acc[mt][nt][r]     = (x1 * cs - x2 * sn) * qsc;
                    acc[mt + 2][nt][r] = (x1 * sn + x2 * cs) * qsc;
                }
            }
        bf16_t* dst = qkvb + (size_t)qkv_idx * QKV_ONE + ((size_t)bm * SEQ + (size_t)tt * HW) * HC;
#pragma unroll
        for (int mt = 0; mt < 4; mt++)
#pragma unroll
            for (int nt = 0; nt < 4; nt++)
#pragma unroll
                for (int r = 0; r < 4; r++) {
                    int cc = mt * 16 + hi * 4 + r;
                    int p  = p0 + wn * 64 + nt * 16 + lo;
                    dst[(size_t)p * HC + cc] = (bf16_t)acc[mt][nt][r];
                }
    } else {
        bf16_t* dst = qkvb + 2 * QKV_ONE + (size_t)bm * HC * SEQ + (size_t)tt * HW;
#pragma unroll
        for (int mt = 0; mt < 4; mt++)
#pragma unroll
            for (int nt = 0; nt < 4; nt++)
#pragma unroll
                for (int r = 0; r < 4; r++) {
                    int cc = mt * 16 + hi * 4 + r;
                    int p  = p0 + wn * 64 + nt * 16 + lo;
                    dst[(size_t)cc * SEQ + p] = (bf16_t)acc[mt][nt][r];
                }
    }
}

// ---------------------------------------------------------------------------
// MFMA flash attention v8: BARRIER-FREE. 3456 independent waves (864 blocks
// x 4 waves); each wave owns 64 queries of one (bm, f, kf) partial and reads
// its K/V fragments DIRECTLY from global — the 4-way intra-block redundancy
// is served by the XCD's L2 (blocks XCD-pinned by bm via idx%8). No
// __syncthreads anywhere; only LDS use is the wave-private swizzled P/O
// transpose buffer. bf16 partial slabs + fp32 l, merged by va_merge.
// ---------------------------------------------------------------------------
__global__ __launch_bounds__(256, 3) void va_attn(const bf16_t* __restrict__ qkvb,
                                                  bf16_t* __restrict__ Opart,
                                                  float* __restrict__ lpart) {
    int idx = blockIdx.x;                   // [0,864)
    int g = idx >> 3;                       // [0,108)
    int bm = (idx & 7) + 8 * (g / 36);      // same-bm -> same idx%8 -> same XCD
    int pidx = g % 36;                      // (f, kf<=f)
    int f = 0;
    while ((f + 1) * (f + 2) / 2 <= pidx) f++;
    int kf = pidx - f * (f + 1) / 2;

    int tid = threadIdx.x;
    int w = tid >> 6, lane = tid & 63;
    int lo = lane & 15, hi = lane >> 4;
    int lx = lo & 7;               // swizzle key

    const bf16_t* qbase = qkvb + (size_t)bm * SEQ * HC;
    const bf16_t* kbase = qkvb + QKV_ONE + (size_t)bm * SEQ * HC;
    const bf16_t* vbase = qkvb + 2 * QKV_ONE + (size_t)bm * HC * SEQ;

    __shared__ bf16_t PBF[4][64 * 64];      // wave-private P^T / O transpose
    bf16_t* PBw = PBF[w];

    // Q B-frags: wave w owns queries f*256 + w*64 .. +63 (q pre-scaled 0.125)
    const bf16_t* qrow = qbase + (size_t)(f * 256 + w * 64 + lo) * HC;
    bf16x8 qf[4][2];
#pragma unroll
    for (int nq = 0; nq < 4; nq++) {
        qf[nq][0] = *(const bf16x8*)(qrow + (size_t)nq * 16 * HC + hi * 8);
        qf[nq][1] = *(const bf16x8*)(qrow + (size_t)nq * 16 * HC + 32 + hi * 8);
    }
    f32x4 o[4][4];
#pragma unroll
    for (int ct = 0; ct < 4; ct++)
#pragma unroll
        for (int nq = 0; nq < 4; nq++) o[ct][nq] = (f32x4){0.f, 0.f, 0.f, 0.f};
    float l4[4] = {0.f, 0.f, 0.f, 0.f};

    for (int kt = 0; kt < 4; kt++) {
        int kpos = kf * 256 + kt * 64;      // absolute key base of this tile
        // ---- K fragments direct from global (wave covers full 64B sectors)
        const bf16_t* kp = kbase + (size_t)(kpos + lo) * HC + hi * 8;
        bf16x8 ka[8];
#pragma unroll
        for (int mt = 0; mt < 4; mt++) {
            ka[2 * mt]     = *(const bf16x8*)(kp + (size_t)mt * 16 * HC);
            ka[2 * mt + 1] = *(const bf16x8*)(kp + (size_t)mt * 16 * HC + 32);
        }
        // ---- S^T = K·Q^T, exp, P^T -> wave-private LDS
#pragma unroll
        for (int mt = 0; mt < 4; mt++) {
#pragma unroll
            for (int nq = 0; nq < 4; nq++) {
                f32x4 s = (f32x4){0.f, 0.f, 0.f, 0.f};
                s = __builtin_amdgcn_mfma_f32_16x16x32_bf16(ka[2 * mt], qf[nq][0], s, 0, 0, 0);
                s = __builtin_amdgcn_mfma_f32_16x16x32_bf16(ka[2 * mt + 1], qf[nq][1], s, 0, 0, 0);
                bf16x4 pk;
#pragma unroll
                for (int r = 0; r < 4; r++) {
                    float p = __expf(s[r]);
                    l4[nq] += p;
                    pk[r] = (bf16_t)p;
                }
                *(bf16x4*)(PBw + (nq * 16 + lo) * 64 +
                           (((2 * mt + (hi >> 1)) ^ lx) * 8) + (hi & 1) * 4) = pk;
            }
        }
        // ---- V fragments direct from global (transposed slab)
        const bf16_t* vp = vbase + (size_t)(lo) * SEQ + kpos + hi * 8;
        bf16x8 va[8];
#pragma unroll
        for (int ct = 0; ct < 4; ct++) {
            va[2 * ct]     = *(const bf16x8*)(vp + (size_t)ct * 16 * SEQ);
            va[2 * ct + 1] = *(const bf16x8*)(vp + (size_t)ct * 16 * SEQ + 32);
        }
        // ---- P^T B-frags back from LDS (same wave, DS in-order)
        bf16x8 pb0[4], pb1[4];
#pragma unroll
        for (int nq = 0; nq < 4; nq++) {
            pb0[nq] = *(const bf16x8*)(PBw + (nq * 16 + lo) * 64 + (hi ^ lx) * 8);
            pb1[nq] = *(const bf16x8*)(PBw + (nq * 16 + lo) * 64 + ((4 + hi) ^ lx) * 8);
        }
        // ---- O^T += V^T·P^T
#pragma unroll
        for (int ct = 0; ct < 4; ct++)
#pragma unroll
            for (int nq = 0; nq < 4; nq++) {
                o[ct][nq] = __builtin_amdgcn_mfma_f32_16x16x32_bf16(va[2 * ct], pb0[nq], o[ct][nq], 0, 0, 0);
                o[ct][nq] = __builtin_amdgcn_mfma_f32_16x16x32_bf16(va[2 * ct + 1], pb1[nq], o[ct][nq], 0, 0, 0);
            }
    }
    // ---- l reduction + store
#pragma unroll
    for (int nq = 0; nq < 4; nq++) {
        l4[nq] += __shfl_xor(l4[nq], 16, 64);
        l4[nq] += __shfl_xor(l4[nq], 32, 64);
    }
    if (hi == 0) {
        float* lb = lpart + (size_t)(bm * 36 + pidx) * 256 + w * 64;
#pragma unroll
        for (int nq = 0; nq < 4; nq++) lb[nq * 16 + lo] = l4[nq];
    }
    // ---- O partial: wave-private LDS transpose -> dense bf16 [q][c] stores
#pragma unroll
    for (int ct = 0; ct < 4; ct++)
#pragma unroll
        for (int nq = 0; nq < 4; nq++) {
            bf16x4 ov;
#pragma unroll
            for (int r = 0; r < 4; r++) ov[r] = (bf16_t)o[ct][nq][r];
            *(bf16x4*)(PBw + (nq * 16 + lo) * 64 +
                       (((2 * ct + (hi >> 1)) ^ lx) * 8) + (hi & 1) * 4) = ov;
        }
    bf16_t* Ob = Opart + (size_t)(bm * 36 + pidx) * 16384 + (size_t)w * 4096;
#pragma unroll
    for (int i = 0; i < 8; i++) {
        int row = i * 8 + (lane >> 3);
        int j   = lane & 7;
        bf16x8 v = *(const bf16x8*)(PBw + row * 64 + ((j ^ (row & 7)) * 8));
        *(bf16x8*)(Ob + (size_t)row * 64 + j * 8) = v;
    }
}

// ---------------------------------------------------------------------------
// merge v4: XCD-remapped, one bf16x8 chunk per thread, dense. (unchanged)
// ---------------------------------------------------------------------------
__global__ __launch_bounds__(256) void va_merge(const bf16_t* __restrict__ Opart,
                                                const float* __restrict__ lpart,
                                                bf16_t* __restrict__ yob) {
    int idx = blockIdx.x;                   // [0,1536)
    int g = idx >> 3;                       // [0,192)
    int bm = (idx & 7) + 8 * (g >> 6);      // same-bm -> same XCD as attn
    int inner = g & 63;
    int rem = inner * 256 + threadIdx.x;    // [0,16384) chunk within bm
    int f    = rem >> 11;
    int rem2 = rem & 2047;
    int q    = rem2 >> 3;
    int c8   = rem2 & 7;
    int sbase = bm * 36 + f * (f + 1) / 2;

    float lsum = 0.f;
    for (int kf = 0; kf <= f; kf++)
        lsum += lpart[(size_t)(sbase + kf) * 256 + q];

    float v[8] = {0.f, 0.f, 0.f, 0.f, 0.f, 0.f, 0.f, 0.f};
    const bf16_t* Ob = Opart + (size_t)sbase * 16384 + (size_t)q * 64 + c8 * 8;
    for (int kf = 0; kf <= f; kf++) {
        bf16x8 pv = *(const bf16x8*)(Ob + (size_t)kf * 16384);
#pragma unroll
        for (int r = 0; r < 8; r++) v[r] += (float)pv[r];
    }

    float invl = 1.0f / lsum;
    int head = bm % 12, b = bm / 12;
    bf16x8 o8;
#pragma unroll
    for (int r = 0; r < 8; r++) o8[r] = (bf16_t)(v[r] * invl);
    *(bf16x8*)(yob + (size_t)(b * 8 + f) * NSTRIDE + (size_t)q * 768 + head * 64 + c8 * 8) = o8;
}

// ---------------------------------------------------------------------------
// Proj GEMM via MFMA + mp_sum. XCD-remapped by n. (unchanged)
// ---------------------------------------------------------------------------
__global__ __launch_bounds__(256, 4) void va_proj_mfma(const bf16_t* __restrict__ Wb,
                                                       const bf16_t* __restrict__ yob,
                                                       const float* __restrict__ x,
                                                       float* __restrict__ out) {
    int idx = blockIdx.x;                   // [0,192)
    int n  = (idx & 7) + 8 * ((idx >> 3) & 1);
    int rest = idx >> 4;                    // [0,12)
    int p0 = (rest & 1) * 128;
    int m0 = (rest >> 1) * 128;             // [0,6)*128
    int tid = threadIdx.x;
    int lane = tid & 63, w = tid >> 6;
    int lo = lane & 15, hi = lane >> 4;
    int wm = w >> 1, wn = w & 1;

    const bf16_t* Ap = Wb + (size_t)(m0 + wm * 64 + lo) * 768 + hi * 8;
    const bf16_t* Bp = yob + (size_t)n * NSTRIDE + (size_t)(p0 + wn * 64 + lo) * 768 + hi * 8;

    f32x4 acc[4][4];
#pragma unroll
    for (int mt = 0; mt < 4; mt++)
#pragma unroll
        for (int nt = 0; nt < 4; nt++) acc[mt][nt] = (f32x4){0.f, 0.f, 0.f, 0.f};

    for (int k0 = 0; k0 < 768; k0 += 32) {
        bf16x8 af[4], bf[4];
#pragma unroll
        for (int mt = 0; mt < 4; mt++)
            af[mt] = *(const bf16x8*)(Ap + (size_t)mt * 16 * 768 + k0);
#pragma unroll
        for (int nt = 0; nt < 4; nt++)
            bf[nt] = *(const bf16x8*)(Bp + (size_t)nt * 16 * 768 + k0);
#pragma unroll
        for (int mt = 0; mt < 4; mt++)
#pragma unroll
            for (int nt = 0; nt < 4; nt++)
                acc[mt][nt] = __builtin_amdgcn_mfma_f32_16x16x32_bf16(af[mt], bf[nt], acc[mt][nt], 0, 0, 0);
    }

    const float* xn = x + (size_t)n * NSTRIDE;
    float* on = out + (size_t)n * NSTRIDE;
#pragma unroll
    for (int mt = 0; mt < 4; mt++)
#pragma unroll
        for (int nt = 0; nt < 4; nt++)
#pragma unroll
            for (int r = 0; r < 4; r++) {
                int oo = m0 + wm * 64 + mt * 16 + hi * 4 + r;
                int p  = p0 + wn * 64 + nt * 16 + lo;
                size_t idx2 = (size_t)oo * 256 + p;
                on[idx2] = (xn[idx2] * 0.7f + acc[mt][nt][r] * 0.3f) * 1.3130643f;
            }
}

// ---------------------------------------------------------------------------
extern "C" void kernel_launch(void* const* d_in, const int* in_sizes, int n_in,
                              void* d_out, int out_size, void* d_ws, size_t ws_size,
                              hipStream_t stream) {
    const float* x     = (const float*)d_in[0];
    const float* wqkv  = (const float*)d_in[1];
    const float* wproj = (const float*)d_in[2];
    float* out = (float*)d_out;

    bf16_t* Opart = (bf16_t*)d_ws;                             // 24*36*16384 bf16
    float*  lpart = (float*)(Opart + (size_t)24 * 36 * 16384); // 24*36*256 fp32
    bf16_t* wqkv_nb  = (bf16_t*)(lpart + (size_t)24 * 36 * 256);
    bf16_t* xt       = wqkv_nb + (size_t)3072 * 768;
    bf16_t* qkvb     = xt + NSTRIDE * 16;
    bf16_t* yob      = qkvb + 3 * QKV_ONE;

    va_prep<<<6144, 256, 0, stream>>>(wqkv, wproj, x, wqkv_nb, xt);
    va_qkv_mfma<<<576, 256, 0, stream>>>(wqkv_nb, xt, qkvb);
    va_attn<<<864, 256, 0, stream>>>(qkvb, Opart, lpart);
    va_merge<<<1536, 256, 0, stream>>>(Opart, lpart, yob);
    va_proj_mfma<<<192, 256, 0, stream>>>(wqkv_nb + (size_t)2304 * 768, yob, x, out);
}